// Round 6
// baseline (284.052 us; speedup 1.0000x reference)
//
#include <hip/hip_runtime.h>
#include <hip/hip_bf16.h>
#include <math.h>

typedef __hip_bfloat16 bf16;
typedef unsigned short u16;
typedef __attribute__((ext_vector_type(8))) short bf16x8;
typedef __attribute__((ext_vector_type(4))) float f32x4;

#define L_SEQ 256
#define NB 4
#define EMB 768
#define NH 12
#define DFF 3072
#define HD 64

__device__ __forceinline__ float ldE(const void* p, size_t i, int f32) {
    return f32 ? ((const float*)p)[i] : __bfloat162float(((const bf16*)p)[i]);
}
__device__ __forceinline__ float b2f(u16 v) { return __uint_as_float(((unsigned)v) << 16); }
__device__ __forceinline__ u16 f2b(float v) {
    bf16 h = __float2bfloat16(v);
    return *(u16*)&h;
}

__device__ __forceinline__ void cvt8(u16* dst, const void* s, size_t off, int f32) {
    if (f32) {
        const float* sf = (const float*)s + off;
        #pragma unroll
        for (int t = 0; t < 8; ++t) dst[t] = f2b(sf[t]);
    } else {
        *(uint4*)dst = *(const uint4*)((const u16*)s + off);
    }
}

// In-block dtype detect: every block reads src's first 256 dwords; fp32 words
// read as bf16 halves show huge exponents.
__device__ __forceinline__ int detect_flag(const void* src, int* lds4) {
    int t = threadIdx.x;            // 256 threads
    int wave = t >> 6, lane = t & 63;
    unsigned w = ((const unsigned*)src)[t];
    unsigned e = ((w & 0xFFFFu) >> 7) & 0xFFu;
    unsigned long long m = __ballot(e >= 0xC3u);
    if (lane == 0) lds4[wave] = __popcll(m);
    __syncthreads();
    return (lds4[0] + lds4[1] + lds4[2] + lds4[3]) > 8 ? 1 : 0;
}

// One kernel packs ALL weights/activations to bf16 and all biases to fp32.
__global__ void pack_all(u16* __restrict__ xb, u16* __restrict__ wqkv,
                         u16* __restrict__ owb, u16* __restrict__ l1b,
                         u16* __restrict__ l2b, float* __restrict__ biasf,
                         const void* src, const void* qw, const void* kw, const void* vw,
                         const void* ow, const void* l1w, const void* l2w,
                         const void* qb, const void* kb, const void* vb,
                         const void* ob, const void* b1, const void* b2,
                         int* __restrict__ flagp) {
    __shared__ int lds4[4];
    const int f32 = detect_flag(src, lds4);
    int b = blockIdx.x;
    if (b == 0 && threadIdx.x == 0) *flagp = f32;   // for later kernels
    if (b >= 3840) {
        int o = (b - 3840) * 256 + threadIdx.x;
        if (o >= 6912) return;
        float v;
        if (o < 768)       v = ldE(qb, o, f32);
        else if (o < 1536) v = ldE(kb, o - 768, f32);
        else if (o < 2304) v = ldE(vb, o - 1536, f32);
        else if (o < 3072) v = ldE(ob, o - 2304, f32);
        else if (o < 6144) v = ldE(b1, o - 3072, f32);
        else               v = ldE(b2, o - 6144, f32);
        biasf[o] = v;
        return;
    }
    int gid = b * 256 + threadIdx.x;
    u16 tmp[8];
    if (gid < 98304) {
        size_t idx = (size_t)gid * 8;
        cvt8(tmp, src, idx, f32);
        *(uint4*)(xb + idx) = *(uint4*)tmp;
    } else if (gid < 319488) {
        size_t idx = (size_t)(gid - 98304) * 8;
        int r = (int)(idx / EMB);
        const void* s;
        size_t off;
        if (r < EMB)          { s = qw; off = idx; }
        else if (r < 2 * EMB) { s = kw; off = idx - (size_t)EMB * EMB; }
        else                  { s = vw; off = idx - (size_t)2 * EMB * EMB; }
        cvt8(tmp, s, off, f32);
        *(uint4*)(wqkv + idx) = *(uint4*)tmp;
    } else if (gid < 393216) {
        size_t idx = (size_t)(gid - 319488) * 8;
        cvt8(tmp, ow, idx, f32);
        *(uint4*)(owb + idx) = *(uint4*)tmp;
    } else if (gid < 688128) {
        size_t idx = (size_t)(gid - 393216) * 8;
        cvt8(tmp, l1w, idx, f32);
        *(uint4*)(l1b + idx) = *(uint4*)tmp;
    } else {
        size_t idx = (size_t)(gid - 688128) * 8;
        cvt8(tmp, l2w, idx, f32);
        *(uint4*)(l2b + idx) = *(uint4*)tmp;
    }
}

// MFMA bf16 GEMM: C[M,N] = A[M,K] @ W[N,K]^T. 64x128 tile (M x N), 4 waves,
// BK=64: HALF the {stage + vmcnt-drain + 2 barriers} sync events of BK=32 at
// identical staged bytes (m233: sync overhead is ~72% of a 2-phase K-step;
// per-step MFMA work doubles 8->16/wave). Double-buffered, prefetch-before-
// compute (T3 minimal). K-summation order identical to BK=32 version.
// MODE 0: +bias, qkv split -> q,k bf16 (q scaled 0.125); V TRANSPOSED vt[n][e][i]
// MODE 2: +bias, GELU -> outB0 bf16, stride DFF
// MODE 4: partial (no bias) -> fp32 to (z ? outF2 : outF)
// MODE 5: partial (no bias) -> atomicAdd into outF
template <int MODE>
__global__ __launch_bounds__(256, 2) void mfma_gemm(
        const u16* __restrict__ A, const u16* __restrict__ W,
        const float* __restrict__ biasf,
        u16* __restrict__ outB0, u16* __restrict__ outB1, u16* __restrict__ outB2,
        float* __restrict__ outF, float* __restrict__ outF2,
        int K, int lda, int ksplit) {
    __shared__ u16 As[2][64 * 64];      // 8KB per buffer
    __shared__ u16 Ws[2][128 * 64];     // 16KB per buffer
    int tid = threadIdx.x;
    int wave = tid >> 6, lane = tid & 63;
    int quad = lane >> 4, col = lane & 15;
    int m0 = blockIdx.y * 64, n0 = blockIdx.x * 128;
    int z = blockIdx.z;
    const u16* Ap = A + (size_t)z * ksplit;
    const u16* Wp = W + (size_t)z * ksplit;
    int wm = (wave >> 1) * 32, wn = (wave & 1) * 64;

    auto stage = [&](int buf, int k0) {
        // A: 64 rows x 64 cols u16 = 8KB = 512 x 16B chunks (2 per thread)
        #pragma unroll
        for (int it = 0; it < 2; ++it) {
            int l = tid + it * 256;
            int r = l >> 3, c8 = (l & 7) * 8;
            const u16* ga = &Ap[(size_t)(m0 + r) * lda + k0 + c8];
            unsigned off = (unsigned)(buf * 8192 + (it * 256 + wave * 64) * 16);
            __builtin_amdgcn_global_load_lds(
                (const __attribute__((address_space(1))) void*)ga,
                (__attribute__((address_space(3))) void*)((char*)As + off),
                16, 0, 0);
        }
        // W: 128 rows x 64 cols u16 = 16KB = 1024 x 16B chunks (4 per thread)
        #pragma unroll
        for (int it = 0; it < 4; ++it) {
            int l = tid + it * 256;
            int r = l >> 3, c8 = (l & 7) * 8;
            const u16* gw = &Wp[(size_t)(n0 + r) * lda + k0 + c8];
            unsigned off = (unsigned)(buf * 16384 + (it * 256 + wave * 64) * 16);
            __builtin_amdgcn_global_load_lds(
                (const __attribute__((address_space(1))) void*)gw,
                (__attribute__((address_space(3))) void*)((char*)Ws + off),
                16, 0, 0);
        }
    };

    f32x4 acc[2][4];
    #pragma unroll
    for (int a = 0; a < 2; ++a)
        #pragma unroll
        for (int b = 0; b < 4; ++b) acc[a][b] = (f32x4){0.f, 0.f, 0.f, 0.f};

    int nt = K >> 6;
    stage(0, 0);
    __syncthreads();                    // compiler drains vmcnt before barrier
    int cur = 0;
    for (int t = 0; t < nt; ++t) {
        if (t + 1 < nt) stage(cur ^ 1, (t + 1) * 64);   // prefetch next tile
        #pragma unroll
        for (int kk = 0; kk < 2; ++kk) {
            bf16x8 af[2], bfr[4];
            #pragma unroll
            for (int mi = 0; mi < 2; ++mi)
                af[mi] = __builtin_bit_cast(bf16x8,
                    *(const uint4*)&As[cur][(wm + mi * 16 + col) * 64 + kk * 32 + quad * 8]);
            #pragma unroll
            for (int ni = 0; ni < 4; ++ni)
                bfr[ni] = __builtin_bit_cast(bf16x8,
                    *(const uint4*)&Ws[cur][(wn + ni * 16 + col) * 64 + kk * 32 + quad * 8]);
            #pragma unroll
            for (int mi = 0; mi < 2; ++mi)
                #pragma unroll
                for (int ni = 0; ni < 4; ++ni)
                    acc[mi][ni] = __builtin_amdgcn_mfma_f32_16x16x32_bf16(
                        af[mi], bfr[ni], acc[mi][ni], 0, 0, 0);
        }
        __syncthreads();                // next buffer written + cur reads done
        cur ^= 1;
    }
    #pragma unroll
    for (int mi = 0; mi < 2; ++mi)
        #pragma unroll
        for (int ni = 0; ni < 4; ++ni)
            #pragma unroll
            for (int reg = 0; reg < 4; ++reg) {
                int rr = m0 + wm + mi * 16 + quad * 4 + reg;
                int cc = n0 + wn + ni * 16 + col;
                float v = acc[mi][ni][reg];
                if (MODE == 0) {
                    v += biasf[cc];
                    if (cc < EMB) {
                        outB0[(size_t)rr * EMB + cc] = f2b(v * 0.125f);
                    } else if (cc < 2 * EMB) {
                        outB1[(size_t)rr * EMB + cc - EMB] = f2b(v);
                    } else {
                        // vt[(n*EMB + e)*L + i], rr = i*NB + n
                        outB2[((size_t)(rr & 3) * EMB + (cc - 2 * EMB)) * L_SEQ + (rr >> 2)] = f2b(v);
                    }
                } else if (MODE == 2) {
                    v += biasf[cc];
                    v = 0.5f * v * (1.0f + erff(v * 0.70710678118654752f));
                    outB0[(size_t)rr * DFF + cc] = f2b(v);
                } else if (MODE == 4) {
                    float* o = z ? outF2 : outF;
                    o[(size_t)rr * EMB + cc] = v;
                } else {
                    atomicAdd(&outF[(size_t)rr * EMB + cc], v);
                }
            }
}

// qp_b[n,i,h,c] (bf16, h padded to 16) = sum_d q[i,n,h,d] p_w[h*64+d, c]
// qpb[n,h,i] = q . p_b   (q pre-scaled by 0.125 in QKV epilogue)
__global__ __launch_bounds__(256) void qp_kernel(
        const u16* __restrict__ qb, const void* __restrict__ p_w,
        const void* __restrict__ p_b, u16* __restrict__ qp_b,
        float* __restrict__ qpb, const int* __restrict__ flagp) {
    const int f32 = *flagp;
    int w = threadIdx.x >> 6, t = threadIdx.x & 63;
    int blk = blockIdx.x * 4 + w;        // (n*NH+h)*L + i
    int i = blk & 255;
    int h = (blk >> 8) % NH;
    int n = blk / (256 * NH);
    __shared__ float qs[4][64];
    qs[w][t] = b2f(qb[(size_t)(i * NB + n) * EMB + h * HD + t]);
    __syncthreads();
    float acc = 0.f;
    #pragma unroll 16
    for (int d = 0; d < 64; ++d)
        acc += qs[w][d] * ldE(p_w, (size_t)(h * HD + d) * HD + t, f32);
    qp_b[(((size_t)(n * L_SEQ + i)) * 16 + h) * 64 + t] = f2b(acc);
    float v = qs[w][t] * ldE(p_b, h * HD + t, f32);
    #pragma unroll
    for (int off = 32; off; off >>= 1) v += __shfl_down(v, off);
    if (t == 0) qpb[blk] = v;
}

// S[n,h,i,j] = sum_c qp_b[n,i,h,c] * pos[n,i,j,c] + qpb[n,h,i]
// One wave / block, j-dim split in 2 (blockIdx.y): 2048 blocks.
__global__ __launch_bounds__(64) void s2_mfma(
        const u16* __restrict__ qp_b, const float* __restrict__ qpb,
        const void* __restrict__ pos, float* __restrict__ S,
        const int* __restrict__ flagp) {
    const int f32 = *flagp;
    int wid = blockIdx.x;                // n*L + i
    int jh = blockIdx.y;                 // 0..1  (j-halves)
    int i = wid & 255, n = wid >> 8;
    int lane = threadIdx.x;
    int quad = lane >> 4, col = lane & 15;
    const u16* qprow = qp_b + (((size_t)wid) * 16 + col) * 64;
    bf16x8 a0 = __builtin_bit_cast(bf16x8, *(const uint4*)(qprow + quad * 8));
    bf16x8 a1 = __builtin_bit_cast(bf16x8, *(const uint4*)(qprow + 32 + quad * 8));
    float qpb_r[4];
    #pragma unroll
    for (int reg = 0; reg < 4; ++reg) {
        int h = quad * 4 + reg;
        qpb_r[reg] = (h < NH) ? qpb[((size_t)n * NH + h) * L_SEQ + i] : 0.f;
    }
    #pragma unroll 4
    for (int tt = 0; tt < 8; ++tt) {
        int t = jh * 8 + tt;
        int j = t * 16 + col;
        size_t pbase = ((size_t)(n * L_SEQ + i) * L_SEQ + j) * HD;
        bf16x8 b0, b1;
        if (f32) {
            const float* pf = (const float*)pos + pbase;
            u16 tmp[16];
            #pragma unroll
            for (int c = 0; c < 8; ++c) tmp[c] = f2b(pf[quad * 8 + c]);
            #pragma unroll
            for (int c = 0; c < 8; ++c) tmp[8 + c] = f2b(pf[32 + quad * 8 + c]);
            b0 = *(bf16x8*)tmp;
            b1 = *(bf16x8*)(tmp + 8);
        } else {
            const u16* pb = (const u16*)pos + pbase;
            b0 = __builtin_bit_cast(bf16x8, *(const uint4*)(pb + quad * 8));
            b1 = __builtin_bit_cast(bf16x8, *(const uint4*)(pb + 32 + quad * 8));
        }
        f32x4 acc = (f32x4){0.f, 0.f, 0.f, 0.f};
        acc = __builtin_amdgcn_mfma_f32_16x16x32_bf16(a0, b0, acc, 0, 0, 0);
        acc = __builtin_amdgcn_mfma_f32_16x16x32_bf16(a1, b1, acc, 0, 0, 0);
        if (quad < 3) {
            #pragma unroll
            for (int reg = 0; reg < 4; ++reg) {
                int h = quad * 4 + reg;
                S[(((size_t)n * NH + h) * L_SEQ + i) * L_SEQ + j] = acc[reg] + qpb_r[reg];
            }
        }
    }
}

// MFMA attention: scores = q.k^T + S, softmax (register+shuffle), ctx = P@V.
// 1 wave per block (16 q-rows), 768 blocks.
__global__ __launch_bounds__(64) void attn3_kernel(
        const u16* __restrict__ qb, const u16* __restrict__ kb,
        const u16* __restrict__ vt, const float* __restrict__ S,
        u16* __restrict__ ctxb) {
    __shared__ u16 p_lds[16][268];
    int b = blockIdx.x;
    int n = b / (NH * 16), rem = b % (NH * 16), h = rem >> 4, it = rem & 15;
    int lane = threadIdx.x;
    int quad = lane >> 4, col = lane & 15;
    int i0 = it * 16;

    const u16* qrow = qb + ((size_t)(i0 + col) * NB + n) * EMB + h * HD;
    bf16x8 a0 = __builtin_bit_cast(bf16x8, *(const uint4*)(qrow + quad * 8));
    bf16x8 a1 = __builtin_bit_cast(bf16x8, *(const uint4*)(qrow + 32 + quad * 8));

    f32x4 sc[16];
    #pragma unroll
    for (int t = 0; t < 16; ++t) {
        const u16* krow = kb + ((size_t)(t * 16 + col) * NB + n) * EMB + h * HD;
        bf16x8 b0 = __builtin_bit_cast(bf16x8, *(const uint4*)(krow + quad * 8));
        bf16x8 b1 = __builtin_bit_cast(bf16x8, *(const uint4*)(krow + 32 + quad * 8));
        f32x4 acc = (f32x4){0.f, 0.f, 0.f, 0.f};
        acc = __builtin_amdgcn_mfma_f32_16x16x32_bf16(a0, b0, acc, 0, 0, 0);
        acc = __builtin_amdgcn_mfma_f32_16x16x32_bf16(a1, b1, acc, 0, 0, 0);
        sc[t] = acc;
    }

    #pragma unroll
    for (int reg = 0; reg < 4; ++reg) {
        const float* Srow = S + (((size_t)n * NH + h) * L_SEQ + i0 + quad * 4 + reg) * L_SEQ + col;
        float m = -1e30f;
        #pragma unroll
        for (int t = 0; t < 16; ++t) {
            float v = sc[t][reg] + Srow[t * 16];
            sc[t][reg] = v;
            m = fmaxf(m, v);
        }
        #pragma unroll
        for (int off = 1; off < 16; off <<= 1) m = fmaxf(m, __shfl_xor(m, off));
        float sum = 0.f;
        #pragma unroll
        for (int t = 0; t < 16; ++t) {
            float e = __expf(sc[t][reg] - m);
            sc[t][reg] = e;
            sum += e;
        }
        #pragma unroll
        for (int off = 1; off < 16; off <<= 1) sum += __shfl_xor(sum, off);
        float inv = 1.0f / sum;
        #pragma unroll
        for (int t = 0; t < 16; ++t)
            p_lds[quad * 4 + reg][t * 16 + col] = f2b(sc[t][reg] * inv);
    }

    bf16x8 ap[8];
    #pragma unroll
    for (int kt = 0; kt < 8; ++kt)
        ap[kt] = __builtin_bit_cast(bf16x8, *(const uint4*)&p_lds[col][kt * 32 + quad * 8]);
    #pragma unroll
    for (int nt = 0; nt < 4; ++nt) {
        const u16* vrow = vt + ((size_t)n * EMB + h * HD + nt * 16 + col) * L_SEQ;
        f32x4 acc = (f32x4){0.f, 0.f, 0.f, 0.f};
        #pragma unroll
        for (int kt = 0; kt < 8; ++kt) {
            bf16x8 bp = __builtin_bit_cast(bf16x8, *(const uint4*)(vrow + kt * 32 + quad * 8));
            acc = __builtin_amdgcn_mfma_f32_16x16x32_bf16(ap[kt], bp, acc, 0, 0, 0);
        }
        #pragma unroll
        for (int reg = 0; reg < 4; ++reg) {
            int ii = i0 + quad * 4 + reg;
            ctxb[((size_t)ii * NB + n) * EMB + h * HD + nt * 16 + col] = f2b(acc[reg]);
        }
    }
}

// Block-wide sum over 256 threads via wave shuffle + 4-word LDS.
__device__ __forceinline__ float blk_sum(float v, volatile float* ws, int wave, int lane) {
    #pragma unroll
    for (int off = 32; off; off >>= 1) v += __shfl_xor(v, off);
    if (lane == 0) ws[wave] = v;
    __syncthreads();
    float s = ws[0] + ws[1] + ws[2] + ws[3];
    __syncthreads();
    return s;
}

// ln1: y = p0 + p1 + src + out_bias; LN -> x1b (bf16); y2 = LN_out + lin2_bias.
__global__ void ln1_kernel(const float* __restrict__ p0, const float* __restrict__ p1,
                           const void* __restrict__ src, const float* __restrict__ biasf,
                           const void* __restrict__ g, const void* __restrict__ b,
                           u16* __restrict__ x1b, float* __restrict__ y2,
                           const int* __restrict__ flagp) {
    const int f32 = *flagp;
    int r = blockIdx.x;
    int t = threadIdx.x;
    int wave = t >> 6, lane = t & 63;
    __shared__ float ws[4];
    float x[3];
    #pragma unroll
    for (int p = 0; p < 3; ++p) {
        int e = t + p * 256;
        size_t oi = (size_t)r * EMB + e;
        x[p] = p0[oi] + p1[oi] + ldE(src, oi, f32) + biasf[2304 + e];
    }
    float mean = blk_sum(x[0] + x[1] + x[2], ws, wave, lane) * (1.0f / EMB);
    float d0 = x[0] - mean, d1 = x[1] - mean, d2 = x[2] - mean;
    float var = blk_sum(d0 * d0 + d1 * d1 + d2 * d2, ws, wave, lane) * (1.0f / EMB);
    float rstd = rsqrtf(var + 1e-5f);
    float vs[3] = {d0, d1, d2};
    #pragma unroll
    for (int p = 0; p < 3; ++p) {
        int e = t + p * 256;
        float v = vs[p] * rstd * ldE(g, e, f32) + ldE(b, e, f32);
        size_t oi = (size_t)r * EMB + e;
        x1b[oi] = f2b(v);
        y2[oi] = v + biasf[6144 + e];
    }
}

// ln2 (final): LN(y2) -> d_out runtime dtype.
__global__ void ln2_kernel(const float* __restrict__ X, const void* __restrict__ g,
                           const void* __restrict__ b, void* __restrict__ outAny,
                           const int* __restrict__ flagp) {
    const int f32 = *flagp;
    int r = blockIdx.x;
    int t = threadIdx.x;
    int wave = t >> 6, lane = t & 63;
    __shared__ float ws[4];
    float x0 = X[(size_t)r * EMB + t];
    float x1 = X[(size_t)r * EMB + t + 256];
    float x2 = X[(size_t)r * EMB + t + 512];
    float mean = blk_sum(x0 + x1 + x2, ws, wave, lane) * (1.0f / EMB);
    float d0 = x0 - mean, d1 = x1 - mean, d2 = x2 - mean;
    float var = blk_sum(d0 * d0 + d1 * d1 + d2 * d2, ws, wave, lane) * (1.0f / EMB);
    float rstd = rsqrtf(var + 1e-5f);
    float vs[3] = {d0, d1, d2};
    #pragma unroll
    for (int p = 0; p < 3; ++p) {
        int e = t + p * 256;
        float v = vs[p] * rstd * ldE(g, e, f32) + ldE(b, e, f32);
        size_t oi = (size_t)r * EMB + e;
        if (f32) ((float*)outAny)[oi] = v;
        else     ((bf16*)outAny)[oi] = __float2bfloat16(v);
    }
}

extern "C" void kernel_launch(void* const* d_in, const int* in_sizes, int n_in,
                              void* d_out, int out_size, void* d_ws, size_t ws_size,
                              hipStream_t stream) {
    const void* src    = d_in[0];
    const void* pos    = d_in[1];
    const void* q_w    = d_in[2];
    const void* q_b    = d_in[3];
    const void* k_w    = d_in[4];
    const void* k_b    = d_in[5];
    const void* v_w    = d_in[6];
    const void* v_b    = d_in[7];
    const void* p_w    = d_in[8];
    const void* p_b    = d_in[9];
    const void* out_w  = d_in[10];
    const void* out_b  = d_in[11];
    const void* lin1_w = d_in[12];
    const void* lin1_b = d_in[13];
    const void* lin2_w = d_in[14];
    const void* lin2_b = d_in[15];
    const void* n1_g   = d_in[16];
    const void* n1_b   = d_in[17];
    const void* n2_g   = d_in[18];
    const void* n2_b   = d_in[19];

    float* f = (float*)d_ws;
    int*   flagp = (int*)f;                              // 16
    float* biasf = f + 16;                               // 6912
    u16*   xb    = (u16*)(f + 6928);                     // 393216 f
    u16*   wqkv  = (u16*)(f + 400144);                   // 884736 f (dead after QKV gemm)
    u16*   owb   = (u16*)(f + 1284880);                  // 294912 f
    u16*   l1b   = (u16*)(f + 1579792);                  // 1179648 f
    u16*   l2b   = (u16*)(f + 2759440);                  // 1179648 f
    u16*   qbp   = (u16*)(f + 3939088);                  // 393216 f
    u16*   kbp   = (u16*)(f + 4332304);                  // 393216 f
    u16*   vtb   = (u16*)(f + 4725520);                  // 393216 f  vt[n][e][i]
    u16*   qp_b  = (u16*)(f + 5118736);                  // 524288 f
    float* qpb   = f + 5643024;                          // 12288
    float* S     = f + 5655312;                          // 3145728 (ends 8801040)
    u16*   ctxb  = (u16*)(f + 8801040);                  // 393216 f (ends 9194256)
    // overlays (regions dead at time of use):
    u16*   ffb   = (u16*)S;                              // S[0 : 1572864]
    float* y2    = S + 1572864;                          // S[1572864 : 2359296]
    float* pOut1 = S + 2359296;                          // S[2359296 : 3145728]
    float* pOut0 = f + 400144;                           // wqkv region (dead)
    u16*   x1b   = vtb;                                  // vt dead after attn3

    pack_all<<<3867, 256, 0, stream>>>(xb, wqkv, owb, l1b, l2b, biasf,
                                       src, q_w, k_w, v_w, out_w, lin1_w, lin2_w,
                                       q_b, k_b, v_b, out_b, lin1_b, lin2_b, flagp);

    // QKV fused GEMM (N=2304); V written transposed. 288 blocks.
    mfma_gemm<0><<<dim3(18, 16), 256, 0, stream>>>(
        xb, wqkv, biasf, qbp, kbp, vtb, nullptr, nullptr, EMB, EMB, 0);

    // position scores
    qp_kernel<<<NB * NH * L_SEQ / 4, 256, 0, stream>>>(qbp, p_w, p_b, qp_b, qpb, flagp);
    s2_mfma<<<dim3(NB * L_SEQ, 2), 64, 0, stream>>>(qp_b, qpb, pos, S, flagp);

    // MFMA attention (1 wave / block, 768 blocks)
    attn3_kernel<<<NB * NH * 16, 64, 0, stream>>>(qbp, kbp, vtb, S, ctxb);

    // out projection, split-K=2 -> partials pOut0/pOut1 (bias+residual in ln1). 192 blocks.
    mfma_gemm<4><<<dim3(6, 16, 2), 256, 0, stream>>>(
        ctxb, owb, nullptr, nullptr, nullptr, nullptr, pOut0, pOut1, 384, EMB, 384);

    // ln1: reduce partials + src + out_bias, LN -> x1b; y2 = LN + lin2_bias
    ln1_kernel<<<1024, 256, 0, stream>>>(pOut0, pOut1, src, biasf, n1_g, n1_b,
                                         x1b, y2, flagp);

    // lin1 + GELU -> ffb. 384 blocks.
    mfma_gemm<2><<<dim3(24, 16), 256, 0, stream>>>(
        x1b, l1b, biasf + 3072, ffb, nullptr, nullptr, nullptr, nullptr, EMB, EMB, 0);

    // lin2, split-K=4, atomic accumulate into y2 (pre-initialized by ln1). 384 blocks.
    mfma_gemm<5><<<dim3(6, 16, 4), 256, 0, stream>>>(
        ffb, l2b, nullptr, nullptr, nullptr, nullptr, y2, nullptr, 768, DFF, 768);

    ln2_kernel<<<1024, 256, 0, stream>>>(y2, n2_g, n2_b, d_out, flagp);
}

// Round 7
// 279.137 us; speedup vs baseline: 1.0176x; 1.0176x over previous
//
#include <hip/hip_runtime.h>
#include <hip/hip_bf16.h>
#include <math.h>

typedef __hip_bfloat16 bf16;
typedef unsigned short u16;
typedef __attribute__((ext_vector_type(8))) short bf16x8;
typedef __attribute__((ext_vector_type(4))) float f32x4;

#define L_SEQ 256
#define NB 4
#define EMB 768
#define NH 12
#define DFF 3072
#define HD 64

__device__ __forceinline__ float ldE(const void* p, size_t i, int f32) {
    return f32 ? ((const float*)p)[i] : __bfloat162float(((const bf16*)p)[i]);
}
__device__ __forceinline__ float b2f(u16 v) { return __uint_as_float(((unsigned)v) << 16); }
__device__ __forceinline__ u16 f2b(float v) {
    bf16 h = __float2bfloat16(v);
    return *(u16*)&h;
}

__device__ __forceinline__ void cvt8(u16* dst, const void* s, size_t off, int f32) {
    if (f32) {
        const float* sf = (const float*)s + off;
        #pragma unroll
        for (int t = 0; t < 8; ++t) dst[t] = f2b(sf[t]);
    } else {
        *(uint4*)dst = *(const uint4*)((const u16*)s + off);
    }
}

// In-block dtype detect: every block reads src's first 256 dwords; fp32 words
// read as bf16 halves show huge exponents.
__device__ __forceinline__ int detect_flag(const void* src, int* lds4) {
    int t = threadIdx.x;            // 256 threads
    int wave = t >> 6, lane = t & 63;
    unsigned w = ((const unsigned*)src)[t];
    unsigned e = ((w & 0xFFFFu) >> 7) & 0xFFu;
    unsigned long long m = __ballot(e >= 0xC3u);
    if (lane == 0) lds4[wave] = __popcll(m);
    __syncthreads();
    return (lds4[0] + lds4[1] + lds4[2] + lds4[3]) > 8 ? 1 : 0;
}

// One kernel packs ALL weights/activations to bf16 and all biases to fp32.
__global__ void pack_all(u16* __restrict__ xb, u16* __restrict__ wqkv,
                         u16* __restrict__ owb, u16* __restrict__ l1b,
                         u16* __restrict__ l2b, float* __restrict__ biasf,
                         const void* src, const void* qw, const void* kw, const void* vw,
                         const void* ow, const void* l1w, const void* l2w,
                         const void* qb, const void* kb, const void* vb,
                         const void* ob, const void* b1, const void* b2,
                         int* __restrict__ flagp) {
    __shared__ int lds4[4];
    const int f32 = detect_flag(src, lds4);
    int b = blockIdx.x;
    if (b == 0 && threadIdx.x == 0) *flagp = f32;   // for later kernels
    if (b >= 3840) {
        int o = (b - 3840) * 256 + threadIdx.x;
        if (o >= 6912) return;
        float v;
        if (o < 768)       v = ldE(qb, o, f32);
        else if (o < 1536) v = ldE(kb, o - 768, f32);
        else if (o < 2304) v = ldE(vb, o - 1536, f32);
        else if (o < 3072) v = ldE(ob, o - 2304, f32);
        else if (o < 6144) v = ldE(b1, o - 3072, f32);
        else               v = ldE(b2, o - 6144, f32);
        biasf[o] = v;
        return;
    }
    int gid = b * 256 + threadIdx.x;
    u16 tmp[8];
    if (gid < 98304) {
        size_t idx = (size_t)gid * 8;
        cvt8(tmp, src, idx, f32);
        *(uint4*)(xb + idx) = *(uint4*)tmp;
    } else if (gid < 319488) {
        size_t idx = (size_t)(gid - 98304) * 8;
        int r = (int)(idx / EMB);
        const void* s;
        size_t off;
        if (r < EMB)          { s = qw; off = idx; }
        else if (r < 2 * EMB) { s = kw; off = idx - (size_t)EMB * EMB; }
        else                  { s = vw; off = idx - (size_t)2 * EMB * EMB; }
        cvt8(tmp, s, off, f32);
        *(uint4*)(wqkv + idx) = *(uint4*)tmp;
    } else if (gid < 393216) {
        size_t idx = (size_t)(gid - 319488) * 8;
        cvt8(tmp, ow, idx, f32);
        *(uint4*)(owb + idx) = *(uint4*)tmp;
    } else if (gid < 688128) {
        size_t idx = (size_t)(gid - 393216) * 8;
        cvt8(tmp, l1w, idx, f32);
        *(uint4*)(l1b + idx) = *(uint4*)tmp;
    } else {
        size_t idx = (size_t)(gid - 688128) * 8;
        cvt8(tmp, l2w, idx, f32);
        *(uint4*)(l2b + idx) = *(uint4*)tmp;
    }
}

// MFMA bf16 GEMM: C[M,N] = A[M,K] @ W[N,K]^T. 64x128 tile (M x N), 4 waves.
// R4 structure (best measured): BK=32, single-buffered, global_load_lds.
// MODE 0: +bias, qkv split -> q,k bf16 HEAD-MAJOR [n][h][i][d] (q scaled
//         0.125); V TRANSPOSED vt[n][e][i]
// MODE 2: +bias, GELU -> outB0 bf16, stride DFF
// MODE 4: partial (no bias) -> fp32 to (z ? outF2 : outF)
// MODE 5: partial (no bias) -> atomicAdd into outF
template <int MODE>
__global__ __launch_bounds__(256, 2) void mfma_gemm(
        const u16* __restrict__ A, const u16* __restrict__ W,
        const float* __restrict__ biasf,
        u16* __restrict__ outB0, u16* __restrict__ outB1, u16* __restrict__ outB2,
        float* __restrict__ outF, float* __restrict__ outF2,
        int K, int lda, int ksplit) {
    __shared__ u16 As[64][32];
    __shared__ u16 Ws[128][32];
    int tid = threadIdx.x;
    int wave = tid >> 6, lane = tid & 63;
    int quad = lane >> 4, col = lane & 15;
    int m0 = blockIdx.y * 64, n0 = blockIdx.x * 128;
    int z = blockIdx.z;
    const u16* Ap = A + (size_t)z * ksplit;
    const u16* Wp = W + (size_t)z * ksplit;
    int wm = (wave >> 1) * 32, wn = (wave & 1) * 64;
    f32x4 acc[2][4];
    #pragma unroll
    for (int a = 0; a < 2; ++a)
        #pragma unroll
        for (int b = 0; b < 4; ++b) acc[a][b] = (f32x4){0.f, 0.f, 0.f, 0.f};
    for (int k0 = 0; k0 < K; k0 += 32) {
        // A: 64x32 el = 4096B = 256 x 16B loads (one per thread)
        {
            int r = tid >> 2, c4 = (tid & 3) * 8;
            const u16* ga = &Ap[(size_t)(m0 + r) * lda + k0 + c4];
            unsigned off = (unsigned)(wave * 64 * 16);
            __builtin_amdgcn_global_load_lds(
                (const __attribute__((address_space(1))) void*)ga,
                (__attribute__((address_space(3))) void*)((char*)&As[0][0] + off),
                16, 0, 0);
        }
        // W: 128x32 el = 8192B = 512 x 16B loads (two per thread)
        #pragma unroll
        for (int it = 0; it < 2; ++it) {
            int l = tid + it * 256;
            int r = l >> 2, c4 = (l & 3) * 8;
            const u16* gw = &Wp[(size_t)(n0 + r) * lda + k0 + c4];
            unsigned off = (unsigned)((it * 256 + wave * 64) * 16);
            __builtin_amdgcn_global_load_lds(
                (const __attribute__((address_space(1))) void*)gw,
                (__attribute__((address_space(3))) void*)((char*)&Ws[0][0] + off),
                16, 0, 0);
        }
        __syncthreads();
        bf16x8 af[2], bfr[4];
        #pragma unroll
        for (int mi = 0; mi < 2; ++mi)
            af[mi] = __builtin_bit_cast(bf16x8, *(const uint4*)&As[wm + mi * 16 + col][quad * 8]);
        #pragma unroll
        for (int ni = 0; ni < 4; ++ni)
            bfr[ni] = __builtin_bit_cast(bf16x8, *(const uint4*)&Ws[wn + ni * 16 + col][quad * 8]);
        #pragma unroll
        for (int mi = 0; mi < 2; ++mi)
            #pragma unroll
            for (int ni = 0; ni < 4; ++ni)
                acc[mi][ni] = __builtin_amdgcn_mfma_f32_16x16x32_bf16(
                    af[mi], bfr[ni], acc[mi][ni], 0, 0, 0);
        __syncthreads();
    }
    #pragma unroll
    for (int mi = 0; mi < 2; ++mi)
        #pragma unroll
        for (int ni = 0; ni < 4; ++ni)
            #pragma unroll
            for (int reg = 0; reg < 4; ++reg) {
                int rr = m0 + wm + mi * 16 + quad * 4 + reg;
                int cc = n0 + wn + ni * 16 + col;
                float v = acc[mi][ni][reg];
                if (MODE == 0) {
                    v += biasf[cc];
                    int i = rr >> 2, n = rr & 3;     // A rows are i*NB+n
                    if (cc < EMB) {
                        // q head-major: [n][h][i][d]
                        int h = cc >> 6, d = cc & 63;
                        outB0[(((size_t)(n * NH + h)) * L_SEQ + i) * HD + d] = f2b(v * 0.125f);
                    } else if (cc < 2 * EMB) {
                        int c2 = cc - EMB;
                        int h = c2 >> 6, d = c2 & 63;
                        outB1[(((size_t)(n * NH + h)) * L_SEQ + i) * HD + d] = f2b(v);
                    } else {
                        // vt[(n*EMB + e)*L + i]
                        outB2[((size_t)n * EMB + (cc - 2 * EMB)) * L_SEQ + i] = f2b(v);
                    }
                } else if (MODE == 2) {
                    v += biasf[cc];
                    v = 0.5f * v * (1.0f + erff(v * 0.70710678118654752f));
                    outB0[(size_t)rr * DFF + cc] = f2b(v);
                } else if (MODE == 4) {
                    float* o = z ? outF2 : outF;
                    o[(size_t)rr * EMB + cc] = v;
                } else {
                    atomicAdd(&outF[(size_t)rr * EMB + cc], v);
                }
            }
}

// qp_b[n,i,h,c] (bf16, h padded to 16) = sum_d q[n,h,i,d] p_w[h*64+d, c]
// qpb[n,h,i] = q . p_b   (q pre-scaled by 0.125 in QKV epilogue)
__global__ __launch_bounds__(256) void qp_kernel(
        const u16* __restrict__ qb, const void* __restrict__ p_w,
        const void* __restrict__ p_b, u16* __restrict__ qp_b,
        float* __restrict__ qpb, const int* __restrict__ flagp) {
    const int f32 = *flagp;
    int w = threadIdx.x >> 6, t = threadIdx.x & 63;
    int blk = blockIdx.x * 4 + w;        // (n*NH+h)*L + i
    int i = blk & 255;
    int h = (blk >> 8) % NH;
    int n = blk / (256 * NH);
    __shared__ float qs[4][64];
    // q head-major: contiguous 128B row per (n,h,i) -> coalesced
    qs[w][t] = b2f(qb[(((size_t)(n * NH + h)) * L_SEQ + i) * HD + t]);
    __syncthreads();
    float acc = 0.f;
    #pragma unroll 16
    for (int d = 0; d < 64; ++d)
        acc += qs[w][d] * ldE(p_w, (size_t)(h * HD + d) * HD + t, f32);
    qp_b[(((size_t)(n * L_SEQ + i)) * 16 + h) * 64 + t] = f2b(acc);
    float v = qs[w][t] * ldE(p_b, h * HD + t, f32);
    #pragma unroll
    for (int off = 32; off; off >>= 1) v += __shfl_down(v, off);
    if (t == 0) qpb[blk] = v;
}

// S[n,h,i,j] = sum_c qp_b[n,i,h,c] * pos[n,i,j,c] + qpb[n,h,i]
// One wave / block, j-dim split in 4 (blockIdx.y): 4096 blocks -> 16 waves/CU
// streaming the 67MB fp32 pos read.
__global__ __launch_bounds__(64) void s2_mfma(
        const u16* __restrict__ qp_b, const float* __restrict__ qpb,
        const void* __restrict__ pos, float* __restrict__ S,
        const int* __restrict__ flagp) {
    const int f32 = *flagp;
    int wid = blockIdx.x;                // n*L + i
    int jh = blockIdx.y;                 // 0..3  (j-quarters)
    int i = wid & 255, n = wid >> 8;
    int lane = threadIdx.x;
    int quad = lane >> 4, col = lane & 15;
    const u16* qprow = qp_b + (((size_t)wid) * 16 + col) * 64;
    bf16x8 a0 = __builtin_bit_cast(bf16x8, *(const uint4*)(qprow + quad * 8));
    bf16x8 a1 = __builtin_bit_cast(bf16x8, *(const uint4*)(qprow + 32 + quad * 8));
    float qpb_r[4];
    #pragma unroll
    for (int reg = 0; reg < 4; ++reg) {
        int h = quad * 4 + reg;
        qpb_r[reg] = (h < NH) ? qpb[((size_t)n * NH + h) * L_SEQ + i] : 0.f;
    }
    #pragma unroll
    for (int tt = 0; tt < 4; ++tt) {
        int t = jh * 4 + tt;
        int j = t * 16 + col;
        size_t pbase = ((size_t)(n * L_SEQ + i) * L_SEQ + j) * HD;
        bf16x8 b0, b1;
        if (f32) {
            const float* pf = (const float*)pos + pbase;
            u16 tmp[16];
            #pragma unroll
            for (int c = 0; c < 8; ++c) tmp[c] = f2b(pf[quad * 8 + c]);
            #pragma unroll
            for (int c = 0; c < 8; ++c) tmp[8 + c] = f2b(pf[32 + quad * 8 + c]);
            b0 = *(bf16x8*)tmp;
            b1 = *(bf16x8*)(tmp + 8);
        } else {
            const u16* pb = (const u16*)pos + pbase;
            b0 = __builtin_bit_cast(bf16x8, *(const uint4*)(pb + quad * 8));
            b1 = __builtin_bit_cast(bf16x8, *(const uint4*)(pb + 32 + quad * 8));
        }
        f32x4 acc = (f32x4){0.f, 0.f, 0.f, 0.f};
        acc = __builtin_amdgcn_mfma_f32_16x16x32_bf16(a0, b0, acc, 0, 0, 0);
        acc = __builtin_amdgcn_mfma_f32_16x16x32_bf16(a1, b1, acc, 0, 0, 0);
        if (quad < 3) {
            #pragma unroll
            for (int reg = 0; reg < 4; ++reg) {
                int h = quad * 4 + reg;
                S[(((size_t)n * NH + h) * L_SEQ + i) * L_SEQ + j] = acc[reg] + qpb_r[reg];
            }
        }
    }
}

// MFMA attention: scores = q.k^T + S, softmax (register+shuffle), ctx = P@V.
// 1 wave per block (16 q-rows), 768 blocks. Q/K head-major -> K-row loads
// are 16 consecutive 128B rows (2KB contiguous) per t-iter.
__global__ __launch_bounds__(64) void attn3_kernel(
        const u16* __restrict__ qb, const u16* __restrict__ kb,
        const u16* __restrict__ vt, const float* __restrict__ S,
        u16* __restrict__ ctxb) {
    __shared__ u16 p_lds[16][268];
    int b = blockIdx.x;
    int n = b / (NH * 16), rem = b % (NH * 16), h = rem >> 4, it = rem & 15;
    int lane = threadIdx.x;
    int quad = lane >> 4, col = lane & 15;
    int i0 = it * 16;

    const u16* qh = qb + ((size_t)(n * NH + h)) * L_SEQ * HD;
    const u16* kh = kb + ((size_t)(n * NH + h)) * L_SEQ * HD;

    const u16* qrow = qh + (size_t)(i0 + col) * HD;
    bf16x8 a0 = __builtin_bit_cast(bf16x8, *(const uint4*)(qrow + quad * 8));
    bf16x8 a1 = __builtin_bit_cast(bf16x8, *(const uint4*)(qrow + 32 + quad * 8));

    f32x4 sc[16];
    #pragma unroll
    for (int t = 0; t < 16; ++t) {
        const u16* krow = kh + (size_t)(t * 16 + col) * HD;
        bf16x8 b0 = __builtin_bit_cast(bf16x8, *(const uint4*)(krow + quad * 8));
        bf16x8 b1 = __builtin_bit_cast(bf16x8, *(const uint4*)(krow + 32 + quad * 8));
        f32x4 acc = (f32x4){0.f, 0.f, 0.f, 0.f};
        acc = __builtin_amdgcn_mfma_f32_16x16x32_bf16(a0, b0, acc, 0, 0, 0);
        acc = __builtin_amdgcn_mfma_f32_16x16x32_bf16(a1, b1, acc, 0, 0, 0);
        sc[t] = acc;
    }

    #pragma unroll
    for (int reg = 0; reg < 4; ++reg) {
        const float* Srow = S + (((size_t)n * NH + h) * L_SEQ + i0 + quad * 4 + reg) * L_SEQ + col;
        float m = -1e30f;
        #pragma unroll
        for (int t = 0; t < 16; ++t) {
            float v = sc[t][reg] + Srow[t * 16];
            sc[t][reg] = v;
            m = fmaxf(m, v);
        }
        #pragma unroll
        for (int off = 1; off < 16; off <<= 1) m = fmaxf(m, __shfl_xor(m, off));
        float sum = 0.f;
        #pragma unroll
        for (int t = 0; t < 16; ++t) {
            float e = __expf(sc[t][reg] - m);
            sc[t][reg] = e;
            sum += e;
        }
        #pragma unroll
        for (int off = 1; off < 16; off <<= 1) sum += __shfl_xor(sum, off);
        float inv = 1.0f / sum;
        #pragma unroll
        for (int t = 0; t < 16; ++t)
            p_lds[quad * 4 + reg][t * 16 + col] = f2b(sc[t][reg] * inv);
    }

    bf16x8 ap[8];
    #pragma unroll
    for (int kt = 0; kt < 8; ++kt)
        ap[kt] = __builtin_bit_cast(bf16x8, *(const uint4*)&p_lds[col][kt * 32 + quad * 8]);
    #pragma unroll
    for (int nt = 0; nt < 4; ++nt) {
        const u16* vrow = vt + ((size_t)n * EMB + h * HD + nt * 16 + col) * L_SEQ;
        f32x4 acc = (f32x4){0.f, 0.f, 0.f, 0.f};
        #pragma unroll
        for (int kt = 0; kt < 8; ++kt) {
            bf16x8 bp = __builtin_bit_cast(bf16x8, *(const uint4*)(vrow + kt * 32 + quad * 8));
            acc = __builtin_amdgcn_mfma_f32_16x16x32_bf16(ap[kt], bp, acc, 0, 0, 0);
        }
        #pragma unroll
        for (int reg = 0; reg < 4; ++reg) {
            int ii = i0 + quad * 4 + reg;
            ctxb[((size_t)ii * NB + n) * EMB + h * HD + nt * 16 + col] = f2b(acc[reg]);
        }
    }
}

// Block-wide sum over 256 threads via wave shuffle + 4-word LDS.
__device__ __forceinline__ float blk_sum(float v, volatile float* ws, int wave, int lane) {
    #pragma unroll
    for (int off = 32; off; off >>= 1) v += __shfl_xor(v, off);
    if (lane == 0) ws[wave] = v;
    __syncthreads();
    float s = ws[0] + ws[1] + ws[2] + ws[3];
    __syncthreads();
    return s;
}

// ln1: y = p0 + p1 + src + out_bias; LN -> x1b (bf16); y2 = LN_out + lin2_bias.
__global__ void ln1_kernel(const float* __restrict__ p0, const float* __restrict__ p1,
                           const void* __restrict__ src, const float* __restrict__ biasf,
                           const void* __restrict__ g, const void* __restrict__ b,
                           u16* __restrict__ x1b, float* __restrict__ y2,
                           const int* __restrict__ flagp) {
    const int f32 = *flagp;
    int r = blockIdx.x;
    int t = threadIdx.x;
    int wave = t >> 6, lane = t & 63;
    __shared__ float ws[4];
    float x[3];
    #pragma unroll
    for (int p = 0; p < 3; ++p) {
        int e = t + p * 256;
        size_t oi = (size_t)r * EMB + e;
        x[p] = p0[oi] + p1[oi] + ldE(src, oi, f32) + biasf[2304 + e];
    }
    float mean = blk_sum(x[0] + x[1] + x[2], ws, wave, lane) * (1.0f / EMB);
    float d0 = x[0] - mean, d1 = x[1] - mean, d2 = x[2] - mean;
    float var = blk_sum(d0 * d0 + d1 * d1 + d2 * d2, ws, wave, lane) * (1.0f / EMB);
    float rstd = rsqrtf(var + 1e-5f);
    float vs[3] = {d0, d1, d2};
    #pragma unroll
    for (int p = 0; p < 3; ++p) {
        int e = t + p * 256;
        float v = vs[p] * rstd * ldE(g, e, f32) + ldE(b, e, f32);
        size_t oi = (size_t)r * EMB + e;
        x1b[oi] = f2b(v);
        y2[oi] = v + biasf[6144 + e];
    }
}

// ln2 (final): LN(y2) -> d_out runtime dtype.
__global__ void ln2_kernel(const float* __restrict__ X, const void* __restrict__ g,
                           const void* __restrict__ b, void* __restrict__ outAny,
                           const int* __restrict__ flagp) {
    const int f32 = *flagp;
    int r = blockIdx.x;
    int t = threadIdx.x;
    int wave = t >> 6, lane = t & 63;
    __shared__ float ws[4];
    float x0 = X[(size_t)r * EMB + t];
    float x1 = X[(size_t)r * EMB + t + 256];
    float x2 = X[(size_t)r * EMB + t + 512];
    float mean = blk_sum(x0 + x1 + x2, ws, wave, lane) * (1.0f / EMB);
    float d0 = x0 - mean, d1 = x1 - mean, d2 = x2 - mean;
    float var = blk_sum(d0 * d0 + d1 * d1 + d2 * d2, ws, wave, lane) * (1.0f / EMB);
    float rstd = rsqrtf(var + 1e-5f);
    float vs[3] = {d0, d1, d2};
    #pragma unroll
    for (int p = 0; p < 3; ++p) {
        int e = t + p * 256;
        float v = vs[p] * rstd * ldE(g, e, f32) + ldE(b, e, f32);
        size_t oi = (size_t)r * EMB + e;
        if (f32) ((float*)outAny)[oi] = v;
        else     ((bf16*)outAny)[oi] = __float2bfloat16(v);
    }
}

extern "C" void kernel_launch(void* const* d_in, const int* in_sizes, int n_in,
                              void* d_out, int out_size, void* d_ws, size_t ws_size,
                              hipStream_t stream) {
    const void* src    = d_in[0];
    const void* pos    = d_in[1];
    const void* q_w    = d_in[2];
    const void* q_b    = d_in[3];
    const void* k_w    = d_in[4];
    const void* k_b    = d_in[5];
    const void* v_w    = d_in[6];
    const void* v_b    = d_in[7];
    const void* p_w    = d_in[8];
    const void* p_b    = d_in[9];
    const void* out_w  = d_in[10];
    const void* out_b  = d_in[11];
    const void* lin1_w = d_in[12];
    const void* lin1_b = d_in[13];
    const void* lin2_w = d_in[14];
    const void* lin2_b = d_in[15];
    const void* n1_g   = d_in[16];
    const void* n1_b   = d_in[17];
    const void* n2_g   = d_in[18];
    const void* n2_b   = d_in[19];

    float* f = (float*)d_ws;
    int*   flagp = (int*)f;                              // 16
    float* biasf = f + 16;                               // 6912
    u16*   xb    = (u16*)(f + 6928);                     // 393216 f
    u16*   wqkv  = (u16*)(f + 400144);                   // 884736 f (dead after QKV gemm)
    u16*   owb   = (u16*)(f + 1284880);                  // 294912 f
    u16*   l1b   = (u16*)(f + 1579792);                  // 1179648 f
    u16*   l2b   = (u16*)(f + 2759440);                  // 1179648 f
    u16*   qbp   = (u16*)(f + 3939088);                  // 393216 f  [n][h][i][d]
    u16*   kbp   = (u16*)(f + 4332304);                  // 393216 f  [n][h][i][d]
    u16*   vtb   = (u16*)(f + 4725520);                  // 393216 f  vt[n][e][i]
    u16*   qp_b  = (u16*)(f + 5118736);                  // 524288 f
    float* qpb   = f + 5643024;                          // 12288
    float* S     = f + 5655312;                          // 3145728 (ends 8801040)
    u16*   ctxb  = (u16*)(f + 8801040);                  // 393216 f (ends 9194256)
    // overlays (regions dead at time of use):
    u16*   ffb   = (u16*)S;                              // S[0 : 1572864]
    float* y2    = S + 1572864;                          // S[1572864 : 2359296]
    float* pOut1 = S + 2359296;                          // S[2359296 : 3145728]
    float* pOut0 = f + 400144;                           // wqkv region (dead)
    u16*   x1b   = vtb;                                  // vt dead after attn3

    pack_all<<<3867, 256, 0, stream>>>(xb, wqkv, owb, l1b, l2b, biasf,
                                       src, q_w, k_w, v_w, out_w, lin1_w, lin2_w,
                                       q_b, k_b, v_b, out_b, lin1_b, lin2_b, flagp);

    // QKV fused GEMM (N=2304); q,k head-major; V transposed. 288 blocks.
    mfma_gemm<0><<<dim3(18, 16), 256, 0, stream>>>(
        xb, wqkv, biasf, qbp, kbp, vtb, nullptr, nullptr, EMB, EMB, 0);

    // position scores
    qp_kernel<<<NB * NH * L_SEQ / 4, 256, 0, stream>>>(qbp, p_w, p_b, qp_b, qpb, flagp);
    s2_mfma<<<dim3(NB * L_SEQ, 4), 64, 0, stream>>>(qp_b, qpb, pos, S, flagp);

    // MFMA attention (1 wave / block, 768 blocks)
    attn3_kernel<<<NB * NH * 16, 64, 0, stream>>>(qbp, kbp, vtb, S, ctxb);

    // out projection, split-K=2 -> partials pOut0/pOut1 (bias+residual in ln1). 192 blocks.
    mfma_gemm<4><<<dim3(6, 16, 2), 256, 0, stream>>>(
        ctxb, owb, nullptr, nullptr, nullptr, nullptr, pOut0, pOut1, 384, EMB, 384);

    // ln1: reduce partials + src + out_bias, LN -> x1b; y2 = LN + lin2_bias
    ln1_kernel<<<1024, 256, 0, stream>>>(pOut0, pOut1, src, biasf, n1_g, n1_b,
                                         x1b, y2, flagp);

    // lin1 + GELU -> ffb. 384 blocks.
    mfma_gemm<2><<<dim3(24, 16), 256, 0, stream>>>(
        x1b, l1b, biasf + 3072, ffb, nullptr, nullptr, nullptr, nullptr, EMB, EMB, 0);

    // lin2, split-K=4, atomic accumulate into y2 (pre-initialized by ln1). 384 blocks.
    mfma_gemm<5><<<dim3(6, 16, 4), 256, 0, stream>>>(
        ffb, l2b, nullptr, nullptr, nullptr, nullptr, y2, nullptr, 768, DFF, 768);

    ln2_kernel<<<1024, 256, 0, stream>>>(y2, n2_g, n2_b, d_out, flagp);
}

// Round 9
// 270.431 us; speedup vs baseline: 1.0504x; 1.0322x over previous
//
#include <hip/hip_runtime.h>
#include <hip/hip_bf16.h>
#include <math.h>

typedef __hip_bfloat16 bf16;
typedef unsigned short u16;
typedef __attribute__((ext_vector_type(8))) short bf16x8;
typedef __attribute__((ext_vector_type(4))) float f32x4;

#define L_SEQ 256
#define NB 4
#define EMB 768
#define NH 12
#define DFF 3072
#define HD 64

__device__ __forceinline__ float ldE(const void* p, size_t i, int f32) {
    return f32 ? ((const float*)p)[i] : __bfloat162float(((const bf16*)p)[i]);
}
__device__ __forceinline__ float b2f(u16 v) { return __uint_as_float(((unsigned)v) << 16); }
__device__ __forceinline__ u16 f2b(float v) {
    bf16 h = __float2bfloat16(v);
    return *(u16*)&h;
}

__device__ __forceinline__ void cvt8(u16* dst, const void* s, size_t off, int f32) {
    if (f32) {
        const float* sf = (const float*)s + off;
        #pragma unroll
        for (int t = 0; t < 8; ++t) dst[t] = f2b(sf[t]);
    } else {
        *(uint4*)dst = *(const uint4*)((const u16*)s + off);
    }
}

// In-block dtype detect: every block reads src's first 256 dwords; fp32 words
// read as bf16 halves show huge exponents.
__device__ __forceinline__ int detect_flag(const void* src, int* lds4) {
    int t = threadIdx.x;            // 256 threads
    int wave = t >> 6, lane = t & 63;
    unsigned w = ((const unsigned*)src)[t];
    unsigned e = ((w & 0xFFFFu) >> 7) & 0xFFu;
    unsigned long long m = __ballot(e >= 0xC3u);
    if (lane == 0) lds4[wave] = __popcll(m);
    __syncthreads();
    return (lds4[0] + lds4[1] + lds4[2] + lds4[3]) > 8 ? 1 : 0;
}

// One kernel packs ALL weights/activations to bf16 and all biases to fp32.
__global__ void pack_all(u16* __restrict__ xb, u16* __restrict__ wqkv,
                         u16* __restrict__ owb, u16* __restrict__ l1b,
                         u16* __restrict__ l2b, float* __restrict__ biasf,
                         const void* src, const void* qw, const void* kw, const void* vw,
                         const void* ow, const void* l1w, const void* l2w,
                         const void* qb, const void* kb, const void* vb,
                         const void* ob, const void* b1, const void* b2,
                         int* __restrict__ flagp) {
    __shared__ int lds4[4];
    const int f32 = detect_flag(src, lds4);
    int b = blockIdx.x;
    if (b == 0 && threadIdx.x == 0) *flagp = f32;   // for later kernels
    if (b >= 3840) {
        int o = (b - 3840) * 256 + threadIdx.x;
        if (o >= 6912) return;
        float v;
        if (o < 768)       v = ldE(qb, o, f32);
        else if (o < 1536) v = ldE(kb, o - 768, f32);
        else if (o < 2304) v = ldE(vb, o - 1536, f32);
        else if (o < 3072) v = ldE(ob, o - 2304, f32);
        else if (o < 6144) v = ldE(b1, o - 3072, f32);
        else               v = ldE(b2, o - 6144, f32);
        biasf[o] = v;
        return;
    }
    int gid = b * 256 + threadIdx.x;
    u16 tmp[8];
    if (gid < 98304) {
        size_t idx = (size_t)gid * 8;
        cvt8(tmp, src, idx, f32);
        *(uint4*)(xb + idx) = *(uint4*)tmp;
    } else if (gid < 319488) {
        size_t idx = (size_t)(gid - 98304) * 8;
        int r = (int)(idx / EMB);
        const void* s;
        size_t off;
        if (r < EMB)          { s = qw; off = idx; }
        else if (r < 2 * EMB) { s = kw; off = idx - (size_t)EMB * EMB; }
        else                  { s = vw; off = idx - (size_t)2 * EMB * EMB; }
        cvt8(tmp, s, off, f32);
        *(uint4*)(wqkv + idx) = *(uint4*)tmp;
    } else if (gid < 393216) {
        size_t idx = (size_t)(gid - 319488) * 8;
        cvt8(tmp, ow, idx, f32);
        *(uint4*)(owb + idx) = *(uint4*)tmp;
    } else if (gid < 688128) {
        size_t idx = (size_t)(gid - 393216) * 8;
        cvt8(tmp, l1w, idx, f32);
        *(uint4*)(l1b + idx) = *(uint4*)tmp;
    } else {
        size_t idx = (size_t)(gid - 688128) * 8;
        cvt8(tmp, l2w, idx, f32);
        *(uint4*)(l2b + idx) = *(uint4*)tmp;
    }
}

// MFMA bf16 GEMM: C[M,N] = A[M,K] @ W[N,K]^T. 64x128 tile (M x N), 4 waves.
// R4 structure (best measured): BK=32, single-buffered, global_load_lds.
// MODE 0: +bias, qkv split -> q,k bf16 HEAD-MAJOR [n][h][i][d] (q scaled
//         0.125); V TRANSPOSED vt[n][e][i]
// MODE 2: +bias, GELU -> outB0 bf16, stride DFF
// MODE 4: partial (no bias) -> fp32 to (z ? outF2 : outF)
// MODE 5: partial (no bias) -> atomicAdd into outF
template <int MODE>
__global__ __launch_bounds__(256, 2) void mfma_gemm(
        const u16* __restrict__ A, const u16* __restrict__ W,
        const float* __restrict__ biasf,
        u16* __restrict__ outB0, u16* __restrict__ outB1, u16* __restrict__ outB2,
        float* __restrict__ outF, float* __restrict__ outF2,
        int K, int lda, int ksplit) {
    __shared__ u16 As[64][32];
    __shared__ u16 Ws[128][32];
    int tid = threadIdx.x;
    int wave = tid >> 6, lane = tid & 63;
    int quad = lane >> 4, col = lane & 15;
    int m0 = blockIdx.y * 64, n0 = blockIdx.x * 128;
    int z = blockIdx.z;
    const u16* Ap = A + (size_t)z * ksplit;
    const u16* Wp = W + (size_t)z * ksplit;
    int wm = (wave >> 1) * 32, wn = (wave & 1) * 64;
    f32x4 acc[2][4];
    #pragma unroll
    for (int a = 0; a < 2; ++a)
        #pragma unroll
        for (int b = 0; b < 4; ++b) acc[a][b] = (f32x4){0.f, 0.f, 0.f, 0.f};
    for (int k0 = 0; k0 < K; k0 += 32) {
        // A: 64x32 el = 4096B = 256 x 16B loads (one per thread)
        {
            int r = tid >> 2, c4 = (tid & 3) * 8;
            const u16* ga = &Ap[(size_t)(m0 + r) * lda + k0 + c4];
            unsigned off = (unsigned)(wave * 64 * 16);
            __builtin_amdgcn_global_load_lds(
                (const __attribute__((address_space(1))) void*)ga,
                (__attribute__((address_space(3))) void*)((char*)&As[0][0] + off),
                16, 0, 0);
        }
        // W: 128x32 el = 8192B = 512 x 16B loads (two per thread)
        #pragma unroll
        for (int it = 0; it < 2; ++it) {
            int l = tid + it * 256;
            int r = l >> 2, c4 = (l & 3) * 8;
            const u16* gw = &Wp[(size_t)(n0 + r) * lda + k0 + c4];
            unsigned off = (unsigned)((it * 256 + wave * 64) * 16);
            __builtin_amdgcn_global_load_lds(
                (const __attribute__((address_space(1))) void*)gw,
                (__attribute__((address_space(3))) void*)((char*)&Ws[0][0] + off),
                16, 0, 0);
        }
        __syncthreads();
        bf16x8 af[2], bfr[4];
        #pragma unroll
        for (int mi = 0; mi < 2; ++mi)
            af[mi] = __builtin_bit_cast(bf16x8, *(const uint4*)&As[wm + mi * 16 + col][quad * 8]);
        #pragma unroll
        for (int ni = 0; ni < 4; ++ni)
            bfr[ni] = __builtin_bit_cast(bf16x8, *(const uint4*)&Ws[wn + ni * 16 + col][quad * 8]);
        #pragma unroll
        for (int mi = 0; mi < 2; ++mi)
            #pragma unroll
            for (int ni = 0; ni < 4; ++ni)
                acc[mi][ni] = __builtin_amdgcn_mfma_f32_16x16x32_bf16(
                    af[mi], bfr[ni], acc[mi][ni], 0, 0, 0);
        __syncthreads();
    }
    #pragma unroll
    for (int mi = 0; mi < 2; ++mi)
        #pragma unroll
        for (int ni = 0; ni < 4; ++ni)
            #pragma unroll
            for (int reg = 0; reg < 4; ++reg) {
                int rr = m0 + wm + mi * 16 + quad * 4 + reg;
                int cc = n0 + wn + ni * 16 + col;
                float v = acc[mi][ni][reg];
                if (MODE == 0) {
                    v += biasf[cc];
                    int i = rr >> 2, n = rr & 3;     // A rows are i*NB+n
                    if (cc < EMB) {
                        // q head-major: [n][h][i][d]
                        int h = cc >> 6, d = cc & 63;
                        outB0[(((size_t)(n * NH + h)) * L_SEQ + i) * HD + d] = f2b(v * 0.125f);
                    } else if (cc < 2 * EMB) {
                        int c2 = cc - EMB;
                        int h = c2 >> 6, d = c2 & 63;
                        outB1[(((size_t)(n * NH + h)) * L_SEQ + i) * HD + d] = f2b(v);
                    } else {
                        // vt[(n*EMB + e)*L + i]
                        outB2[((size_t)n * EMB + (cc - 2 * EMB)) * L_SEQ + i] = f2b(v);
                    }
                } else if (MODE == 2) {
                    v += biasf[cc];
                    v = 0.5f * v * (1.0f + erff(v * 0.70710678118654752f));
                    outB0[(size_t)rr * DFF + cc] = f2b(v);
                } else if (MODE == 4) {
                    float* o = z ? outF2 : outF;
                    o[(size_t)rr * EMB + cc] = v;
                } else {
                    atomicAdd(&outF[(size_t)rr * EMB + cc], v);
                }
            }
}

// qp_b[n,i,h,c] (bf16, h padded to 16) = sum_d q[n,h,i,d] p_w[h*64+d, c]
// qpb[n,h,i] = q . p_b   (q pre-scaled by 0.125 in QKV epilogue)
__global__ __launch_bounds__(256) void qp_kernel(
        const u16* __restrict__ qb, const void* __restrict__ p_w,
        const void* __restrict__ p_b, u16* __restrict__ qp_b,
        float* __restrict__ qpb, const int* __restrict__ flagp) {
    const int f32 = *flagp;
    int w = threadIdx.x >> 6, t = threadIdx.x & 63;
    int blk = blockIdx.x * 4 + w;        // (n*NH+h)*L + i
    int i = blk & 255;
    int h = (blk >> 8) % NH;
    int n = blk / (256 * NH);
    __shared__ float qs[4][64];
    // q head-major: contiguous 128B row per (n,h,i) -> coalesced
    qs[w][t] = b2f(qb[(((size_t)(n * NH + h)) * L_SEQ + i) * HD + t]);
    __syncthreads();
    float acc = 0.f;
    #pragma unroll 16
    for (int d = 0; d < 64; ++d)
        acc += qs[w][d] * ldE(p_w, (size_t)(h * HD + d) * HD + t, f32);
    qp_b[(((size_t)(n * L_SEQ + i)) * 16 + h) * 64 + t] = f2b(acc);
    float v = qs[w][t] * ldE(p_b, h * HD + t, f32);
    #pragma unroll
    for (int off = 32; off; off >>= 1) v += __shfl_down(v, off);
    if (t == 0) qpb[blk] = v;
}

// S[n,h,i,j] = sum_c qp_b[n,i,h,c] * pos[n,i,j,c] + qpb[n,h,i]
// One wave / block, j-dim split in 4 (blockIdx.y): 4096 blocks.
__global__ __launch_bounds__(64) void s2_mfma(
        const u16* __restrict__ qp_b, const float* __restrict__ qpb,
        const void* __restrict__ pos, float* __restrict__ S,
        const int* __restrict__ flagp) {
    const int f32 = *flagp;
    int wid = blockIdx.x;                // n*L + i
    int jh = blockIdx.y;                 // 0..3  (j-quarters)
    int i = wid & 255, n = wid >> 8;
    int lane = threadIdx.x;
    int quad = lane >> 4, col = lane & 15;
    const u16* qprow = qp_b + (((size_t)wid) * 16 + col) * 64;
    bf16x8 a0 = __builtin_bit_cast(bf16x8, *(const uint4*)(qprow + quad * 8));
    bf16x8 a1 = __builtin_bit_cast(bf16x8, *(const uint4*)(qprow + 32 + quad * 8));
    float qpb_r[4];
    #pragma unroll
    for (int reg = 0; reg < 4; ++reg) {
        int h = quad * 4 + reg;
        qpb_r[reg] = (h < NH) ? qpb[((size_t)n * NH + h) * L_SEQ + i] : 0.f;
    }
    #pragma unroll
    for (int tt = 0; tt < 4; ++tt) {
        int t = jh * 4 + tt;
        int j = t * 16 + col;
        size_t pbase = ((size_t)(n * L_SEQ + i) * L_SEQ + j) * HD;
        bf16x8 b0, b1;
        if (f32) {
            const float* pf = (const float*)pos + pbase;
            u16 tmp[16];
            #pragma unroll
            for (int c = 0; c < 8; ++c) tmp[c] = f2b(pf[quad * 8 + c]);
            #pragma unroll
            for (int c = 0; c < 8; ++c) tmp[8 + c] = f2b(pf[32 + quad * 8 + c]);
            b0 = *(bf16x8*)tmp;
            b1 = *(bf16x8*)(tmp + 8);
        } else {
            const u16* pb = (const u16*)pos + pbase;
            b0 = __builtin_bit_cast(bf16x8, *(const uint4*)(pb + quad * 8));
            b1 = __builtin_bit_cast(bf16x8, *(const uint4*)(pb + 32 + quad * 8));
        }
        f32x4 acc = (f32x4){0.f, 0.f, 0.f, 0.f};
        acc = __builtin_amdgcn_mfma_f32_16x16x32_bf16(a0, b0, acc, 0, 0, 0);
        acc = __builtin_amdgcn_mfma_f32_16x16x32_bf16(a1, b1, acc, 0, 0, 0);
        if (quad < 3) {
            #pragma unroll
            for (int reg = 0; reg < 4; ++reg) {
                int h = quad * 4 + reg;
                S[(((size_t)n * NH + h) * L_SEQ + i) * L_SEQ + j] = acc[reg] + qpb_r[reg];
            }
        }
    }
}

// MFMA attention, 4 waves per block cooperating on ONE 16-row i-tile:
// wave w owns j-quarter [w*64,(w+1)*64) for QK^T+partial softmax, and
// output-column group nt=w for PV. Partial max/sum combined via LDS
// (exact: global max = max of partials; sums taken against global max).
// 768 blocks x 4 waves = 12 waves/CU (was 3) -- latency hiding on the
// K/S/V streams.
__global__ __launch_bounds__(256) void attn3_kernel(
        const u16* __restrict__ qb, const u16* __restrict__ kb,
        const u16* __restrict__ vt, const float* __restrict__ S,
        u16* __restrict__ ctxb) {
    __shared__ u16 p_lds[16][268];
    __shared__ float lds_m[4][16];
    __shared__ float lds_s[4][16];
    int b = blockIdx.x;
    int n = b / (NH * 16), rem = b % (NH * 16), h = rem >> 4, it = rem & 15;
    int wave = threadIdx.x >> 6, lane = threadIdx.x & 63;
    int quad = lane >> 4, col = lane & 15;
    int i0 = it * 16;

    const u16* qh = qb + ((size_t)(n * NH + h)) * L_SEQ * HD;
    const u16* kh = kb + ((size_t)(n * NH + h)) * L_SEQ * HD;

    const u16* qrow = qh + (size_t)(i0 + col) * HD;
    bf16x8 a0 = __builtin_bit_cast(bf16x8, *(const uint4*)(qrow + quad * 8));
    bf16x8 a1 = __builtin_bit_cast(bf16x8, *(const uint4*)(qrow + 32 + quad * 8));

    // QK^T for this wave's 4 j-tiles
    f32x4 sc[4];
    #pragma unroll
    for (int tt = 0; tt < 4; ++tt) {
        int t = wave * 4 + tt;
        const u16* krow = kh + (size_t)(t * 16 + col) * HD;
        bf16x8 b0 = __builtin_bit_cast(bf16x8, *(const uint4*)(krow + quad * 8));
        bf16x8 b1 = __builtin_bit_cast(bf16x8, *(const uint4*)(krow + 32 + quad * 8));
        f32x4 acc = (f32x4){0.f, 0.f, 0.f, 0.f};
        acc = __builtin_amdgcn_mfma_f32_16x16x32_bf16(a0, b0, acc, 0, 0, 0);
        acc = __builtin_amdgcn_mfma_f32_16x16x32_bf16(a1, b1, acc, 0, 0, 0);
        sc[tt] = acc;
    }

    // phase A: add S, per-wave partial row max
    #pragma unroll
    for (int reg = 0; reg < 4; ++reg) {
        const float* Srow = S + (((size_t)n * NH + h) * L_SEQ + i0 + quad * 4 + reg) * L_SEQ + col;
        float m = -1e30f;
        #pragma unroll
        for (int tt = 0; tt < 4; ++tt) {
            float v = sc[tt][reg] + Srow[(wave * 4 + tt) * 16];
            sc[tt][reg] = v;
            m = fmaxf(m, v);
        }
        #pragma unroll
        for (int off = 1; off < 16; off <<= 1) m = fmaxf(m, __shfl_xor(m, off));
        if (col == 0) lds_m[wave][quad * 4 + reg] = m;
    }
    __syncthreads();
    // global max per row
    float gm[4];
    #pragma unroll
    for (int reg = 0; reg < 4; ++reg) {
        int row = quad * 4 + reg;
        gm[reg] = fmaxf(fmaxf(lds_m[0][row], lds_m[1][row]),
                        fmaxf(lds_m[2][row], lds_m[3][row]));
    }
    // phase B: exp against global max, per-wave partial sums
    #pragma unroll
    for (int reg = 0; reg < 4; ++reg) {
        float sum = 0.f;
        #pragma unroll
        for (int tt = 0; tt < 4; ++tt) {
            float e = __expf(sc[tt][reg] - gm[reg]);
            sc[tt][reg] = e;
            sum += e;
        }
        #pragma unroll
        for (int off = 1; off < 16; off <<= 1) sum += __shfl_xor(sum, off);
        if (col == 0) lds_s[wave][quad * 4 + reg] = sum;
    }
    __syncthreads();
    // phase C: normalize, write P (this wave's j-quarter)
    #pragma unroll
    for (int reg = 0; reg < 4; ++reg) {
        int row = quad * 4 + reg;
        float gs = lds_s[0][row] + lds_s[1][row] + lds_s[2][row] + lds_s[3][row];
        float inv = 1.0f / gs;
        #pragma unroll
        for (int tt = 0; tt < 4; ++tt)
            p_lds[row][(wave * 4 + tt) * 16 + col] = f2b(sc[tt][reg] * inv);
    }
    __syncthreads();

    // PV: wave w computes output columns h*64 + w*16 + col
    bf16x8 ap[8];
    #pragma unroll
    for (int kt = 0; kt < 8; ++kt)
        ap[kt] = __builtin_bit_cast(bf16x8, *(const uint4*)&p_lds[col][kt * 32 + quad * 8]);
    {
        const u16* vrow = vt + ((size_t)n * EMB + h * HD + wave * 16 + col) * L_SEQ;
        f32x4 acc = (f32x4){0.f, 0.f, 0.f, 0.f};
        #pragma unroll
        for (int kt = 0; kt < 8; ++kt) {
            bf16x8 bp = __builtin_bit_cast(bf16x8, *(const uint4*)(vrow + kt * 32 + quad * 8));
            acc = __builtin_amdgcn_mfma_f32_16x16x32_bf16(ap[kt], bp, acc, 0, 0, 0);
        }
        #pragma unroll
        for (int reg = 0; reg < 4; ++reg) {
            int ii = i0 + quad * 4 + reg;
            ctxb[((size_t)ii * NB + n) * EMB + h * HD + wave * 16 + col] = f2b(acc[reg]);
        }
    }
}

// Block-wide sum over 256 threads via wave shuffle + 4-word LDS.
__device__ __forceinline__ float blk_sum(float v, volatile float* ws, int wave, int lane) {
    #pragma unroll
    for (int off = 32; off; off >>= 1) v += __shfl_xor(v, off);
    if (lane == 0) ws[wave] = v;
    __syncthreads();
    float s = ws[0] + ws[1] + ws[2] + ws[3];
    __syncthreads();
    return s;
}

// ln1: y = p0 + p1 + src + out_bias; LN -> x1b (bf16); y2 = LN_out + lin2_bias.
__global__ void ln1_kernel(const float* __restrict__ p0, const float* __restrict__ p1,
                           const void* __restrict__ src, const float* __restrict__ biasf,
                           const void* __restrict__ g, const void* __restrict__ b,
                           u16* __restrict__ x1b, float* __restrict__ y2,
                           const int* __restrict__ flagp) {
    const int f32 = *flagp;
    int r = blockIdx.x;
    int t = threadIdx.x;
    int wave = t >> 6, lane = t & 63;
    __shared__ float ws[4];
    float x[3];
    #pragma unroll
    for (int p = 0; p < 3; ++p) {
        int e = t + p * 256;
        size_t oi = (size_t)r * EMB + e;
        x[p] = p0[oi] + p1[oi] + ldE(src, oi, f32) + biasf[2304 + e];
    }
    float mean = blk_sum(x[0] + x[1] + x[2], ws, wave, lane) * (1.0f / EMB);
    float d0 = x[0] - mean, d1 = x[1] - mean, d2 = x[2] - mean;
    float var = blk_sum(d0 * d0 + d1 * d1 + d2 * d2, ws, wave, lane) * (1.0f / EMB);
    float rstd = rsqrtf(var + 1e-5f);
    float vs[3] = {d0, d1, d2};
    #pragma unroll
    for (int p = 0; p < 3; ++p) {
        int e = t + p * 256;
        float v = vs[p] * rstd * ldE(g, e, f32) + ldE(b, e, f32);
        size_t oi = (size_t)r * EMB + e;
        x1b[oi] = f2b(v);
        y2[oi] = v + biasf[6144 + e];
    }
}

// ln2 (final): LN(y2) -> d_out runtime dtype.
__global__ void ln2_kernel(const float* __restrict__ X, const void* __restrict__ g,
                           const void* __restrict__ b, void* __restrict__ outAny,
                           const int* __restrict__ flagp) {
    const int f32 = *flagp;
    int r = blockIdx.x;
    int t = threadIdx.x;
    int wave = t >> 6, lane = t & 63;
    __shared__ float ws[4];
    float x0 = X[(size_t)r * EMB + t];
    float x1 = X[(size_t)r * EMB + t + 256];
    float x2 = X[(size_t)r * EMB + t + 512];
    float mean = blk_sum(x0 + x1 + x2, ws, wave, lane) * (1.0f / EMB);
    float d0 = x0 - mean, d1 = x1 - mean, d2 = x2 - mean;
    float var = blk_sum(d0 * d0 + d1 * d1 + d2 * d2, ws, wave, lane) * (1.0f / EMB);
    float rstd = rsqrtf(var + 1e-5f);
    float vs[3] = {d0, d1, d2};
    #pragma unroll
    for (int p = 0; p < 3; ++p) {
        int e = t + p * 256;
        float v = vs[p] * rstd * ldE(g, e, f32) + ldE(b, e, f32);
        size_t oi = (size_t)r * EMB + e;
        if (f32) ((float*)outAny)[oi] = v;
        else     ((bf16*)outAny)[oi] = __float2bfloat16(v);
    }
}

extern "C" void kernel_launch(void* const* d_in, const int* in_sizes, int n_in,
                              void* d_out, int out_size, void* d_ws, size_t ws_size,
                              hipStream_t stream) {
    const void* src    = d_in[0];
    const void* pos    = d_in[1];
    const void* q_w    = d_in[2];
    const void* q_b    = d_in[3];
    const void* k_w    = d_in[4];
    const void* k_b    = d_in[5];
    const void* v_w    = d_in[6];
    const void* v_b    = d_in[7];
    const void* p_w    = d_in[8];
    const void* p_b    = d_in[9];
    const void* out_w  = d_in[10];
    const void* out_b  = d_in[11];
    const void* lin1_w = d_in[12];
    const void* lin1_b = d_in[13];
    const void* lin2_w = d_in[14];
    const void* lin2_b = d_in[15];
    const void* n1_g   = d_in[16];
    const void* n1_b   = d_in[17];
    const void* n2_g   = d_in[18];
    const void* n2_b   = d_in[19];

    float* f = (float*)d_ws;
    int*   flagp = (int*)f;                              // 16
    float* biasf = f + 16;                               // 6912
    u16*   xb    = (u16*)(f + 6928);                     // 393216 f
    u16*   wqkv  = (u16*)(f + 400144);                   // 884736 f (dead after QKV gemm)
    u16*   owb   = (u16*)(f + 1284880);                  // 294912 f
    u16*   l1b   = (u16*)(f + 1579792);                  // 1179648 f
    u16*   l2b   = (u16*)(f + 2759440);                  // 1179648 f
    u16*   qbp   = (u16*)(f + 3939088);                  // 393216 f  [n][h][i][d]
    u16*   kbp   = (u16*)(f + 4332304);                  // 393216 f  [n][h][i][d]
    u16*   vtb   = (u16*)(f + 4725520);                  // 393216 f  vt[n][e][i]
    u16*   qp_b  = (u16*)(f + 5118736);                  // 524288 f
    float* qpb   = f + 5643024;                          // 12288
    float* S     = f + 5655312;                          // 3145728 (ends 8801040)
    u16*   ctxb  = (u16*)(f + 8801040);                  // 393216 f (ends 9194256)
    // overlays (regions dead at time of use):
    u16*   ffb   = (u16*)S;                              // S[0 : 1572864]
    float* y2    = S + 1572864;                          // S[1572864 : 2359296]
    float* pOut1 = S + 2359296;                          // S[2359296 : 3145728]
    float* pOut0 = f + 400144;                           // wqkv region (dead)
    u16*   x1b   = vtb;                                  // vt dead after attn3

    pack_all<<<3867, 256, 0, stream>>>(xb, wqkv, owb, l1b, l2b, biasf,
                                       src, q_w, k_w, v_w, out_w, lin1_w, lin2_w,
                                       q_b, k_b, v_b, out_b, lin1_b, lin2_b, flagp);

    // QKV fused GEMM (N=2304); q,k head-major; V transposed. 288 blocks.
    mfma_gemm<0><<<dim3(18, 16), 256, 0, stream>>>(
        xb, wqkv, biasf, qbp, kbp, vtb, nullptr, nullptr, EMB, EMB, 0);

    // position scores
    qp_kernel<<<NB * NH * L_SEQ / 4, 256, 0, stream>>>(qbp, p_w, p_b, qp_b, qpb, flagp);
    s2_mfma<<<dim3(NB * L_SEQ, 4), 64, 0, stream>>>(qp_b, qpb, pos, S, flagp);

    // MFMA attention (4 coop waves / block, 768 blocks = 12 waves/CU)
    attn3_kernel<<<NB * NH * 16, 256, 0, stream>>>(qbp, kbp, vtb, S, ctxb);

    // out projection, split-K=2 -> partials pOut0/pOut1 (bias+residual in ln1). 192 blocks.
    mfma_gemm<4><<<dim3(6, 16, 2), 256, 0, stream>>>(
        ctxb, owb, nullptr, nullptr, nullptr, nullptr, pOut0, pOut1, 384, EMB, 384);

    // ln1: reduce partials + src + out_bias, LN -> x1b; y2 = LN + lin2_bias
    ln1_kernel<<<1024, 256, 0, stream>>>(pOut0, pOut1, src, biasf, n1_g, n1_b,
                                         x1b, y2, flagp);

    // lin1 + GELU -> ffb. 384 blocks.
    mfma_gemm<2><<<dim3(24, 16), 256, 0, stream>>>(
        x1b, l1b, biasf + 3072, ffb, nullptr, nullptr, nullptr, nullptr, EMB, EMB, 0);

    // lin2, split-K=4, atomic accumulate into y2 (pre-initialized by ln1). 384 blocks.
    mfma_gemm<5><<<dim3(6, 16, 4), 256, 0, stream>>>(
        ffb, l2b, nullptr, nullptr, nullptr, nullptr, y2, nullptr, 768, DFF, 768);

    ln2_kernel<<<1024, 256, 0, stream>>>(y2, n2_g, n2_b, d_out, flagp);
}

// Round 10
// 263.880 us; speedup vs baseline: 1.0764x; 1.0248x over previous
//
#include <hip/hip_runtime.h>
#include <hip/hip_bf16.h>
#include <math.h>

typedef __hip_bfloat16 bf16;
typedef unsigned short u16;
typedef __attribute__((ext_vector_type(8))) short bf16x8;
typedef __attribute__((ext_vector_type(4))) float f32x4;

#define L_SEQ 256
#define NB 4
#define EMB 768
#define NH 12
#define DFF 3072
#define HD 64

__device__ __forceinline__ float ldE(const void* p, size_t i, int f32) {
    return f32 ? ((const float*)p)[i] : __bfloat162float(((const bf16*)p)[i]);
}
__device__ __forceinline__ float b2f(u16 v) { return __uint_as_float(((unsigned)v) << 16); }
__device__ __forceinline__ u16 f2b(float v) {
    bf16 h = __float2bfloat16(v);
    return *(u16*)&h;
}

__device__ __forceinline__ void cvt8(u16* dst, const void* s, size_t off, int f32) {
    if (f32) {
        const float* sf = (const float*)s + off;
        #pragma unroll
        for (int t = 0; t < 8; ++t) dst[t] = f2b(sf[t]);
    } else {
        *(uint4*)dst = *(const uint4*)((const u16*)s + off);
    }
}

// In-block dtype detect: every block reads src's first 256 dwords; fp32 words
// read as bf16 halves show huge exponents.
__device__ __forceinline__ int detect_flag(const void* src, int* lds4) {
    int t = threadIdx.x;            // 256 threads
    int wave = t >> 6, lane = t & 63;
    unsigned w = ((const unsigned*)src)[t];
    unsigned e = ((w & 0xFFFFu) >> 7) & 0xFFu;
    unsigned long long m = __ballot(e >= 0xC3u);
    if (lane == 0) lds4[wave] = __popcll(m);
    __syncthreads();
    return (lds4[0] + lds4[1] + lds4[2] + lds4[3]) > 8 ? 1 : 0;
}

// One kernel packs ALL weights/activations to bf16 and all biases to fp32.
__global__ void pack_all(u16* __restrict__ xb, u16* __restrict__ wqkv,
                         u16* __restrict__ owb, u16* __restrict__ l1b,
                         u16* __restrict__ l2b, float* __restrict__ biasf,
                         const void* src, const void* qw, const void* kw, const void* vw,
                         const void* ow, const void* l1w, const void* l2w,
                         const void* qb, const void* kb, const void* vb,
                         const void* ob, const void* b1, const void* b2,
                         int* __restrict__ flagp) {
    __shared__ int lds4[4];
    const int f32 = detect_flag(src, lds4);
    int b = blockIdx.x;
    if (b == 0 && threadIdx.x == 0) *flagp = f32;   // for later kernels
    if (b >= 3840) {
        int o = (b - 3840) * 256 + threadIdx.x;
        if (o >= 6912) return;
        float v;
        if (o < 768)       v = ldE(qb, o, f32);
        else if (o < 1536) v = ldE(kb, o - 768, f32);
        else if (o < 2304) v = ldE(vb, o - 1536, f32);
        else if (o < 3072) v = ldE(ob, o - 2304, f32);
        else if (o < 6144) v = ldE(b1, o - 3072, f32);
        else               v = ldE(b2, o - 6144, f32);
        biasf[o] = v;
        return;
    }
    int gid = b * 256 + threadIdx.x;
    u16 tmp[8];
    if (gid < 98304) {
        size_t idx = (size_t)gid * 8;
        cvt8(tmp, src, idx, f32);
        *(uint4*)(xb + idx) = *(uint4*)tmp;
    } else if (gid < 319488) {
        size_t idx = (size_t)(gid - 98304) * 8;
        int r = (int)(idx / EMB);
        const void* s;
        size_t off;
        if (r < EMB)          { s = qw; off = idx; }
        else if (r < 2 * EMB) { s = kw; off = idx - (size_t)EMB * EMB; }
        else                  { s = vw; off = idx - (size_t)2 * EMB * EMB; }
        cvt8(tmp, s, off, f32);
        *(uint4*)(wqkv + idx) = *(uint4*)tmp;
    } else if (gid < 393216) {
        size_t idx = (size_t)(gid - 319488) * 8;
        cvt8(tmp, ow, idx, f32);
        *(uint4*)(owb + idx) = *(uint4*)tmp;
    } else if (gid < 688128) {
        size_t idx = (size_t)(gid - 393216) * 8;
        cvt8(tmp, l1w, idx, f32);
        *(uint4*)(l1b + idx) = *(uint4*)tmp;
    } else {
        size_t idx = (size_t)(gid - 688128) * 8;
        cvt8(tmp, l2w, idx, f32);
        *(uint4*)(l2b + idx) = *(uint4*)tmp;
    }
}

// MFMA bf16 GEMM: C[M,N] = A[M,K] @ W[N,K]^T. 64x64 tile, 4 waves x 32x32.
// LDS 8KB, launch_bounds(256,3): 3+ blocks/CU resident so each block's
// vmcnt(0)+barrier drain overlaps other blocks' MFMA (m114 mechanism --
// the only GEMM lever that measured positive on this workload, R2->R4).
// MODE 0: +bias, qkv split -> q,k bf16 HEAD-MAJOR [n][h][i][d] (q scaled
//         0.125); V TRANSPOSED vt[n][e][i]
// MODE 2: +bias, GELU -> outB0 bf16, stride DFF
// MODE 4: partial (no bias) -> fp32 to (z ? outF2 : outF)
// MODE 5: partial (no bias) -> atomicAdd into outF
template <int MODE>
__global__ __launch_bounds__(256, 3) void mfma_gemm(
        const u16* __restrict__ A, const u16* __restrict__ W,
        const float* __restrict__ biasf,
        u16* __restrict__ outB0, u16* __restrict__ outB1, u16* __restrict__ outB2,
        float* __restrict__ outF, float* __restrict__ outF2,
        int K, int lda, int ksplit) {
    __shared__ u16 As[64][32];
    __shared__ u16 Ws[64][32];
    int tid = threadIdx.x;
    int wave = tid >> 6, lane = tid & 63;
    int quad = lane >> 4, col = lane & 15;
    int m0 = blockIdx.y * 64, n0 = blockIdx.x * 64;
    int z = blockIdx.z;
    const u16* Ap = A + (size_t)z * ksplit;
    const u16* Wp = W + (size_t)z * ksplit;
    int wm = (wave >> 1) * 32, wn = (wave & 1) * 32;
    f32x4 acc[2][2];
    #pragma unroll
    for (int a = 0; a < 2; ++a)
        #pragma unroll
        for (int b = 0; b < 2; ++b) acc[a][b] = (f32x4){0.f, 0.f, 0.f, 0.f};
    for (int k0 = 0; k0 < K; k0 += 32) {
        // A: 64x32 el = 4096B = 256 x 16B loads (one per thread)
        {
            int r = tid >> 2, c4 = (tid & 3) * 8;
            const u16* ga = &Ap[(size_t)(m0 + r) * lda + k0 + c4];
            unsigned off = (unsigned)(wave * 64 * 16);
            __builtin_amdgcn_global_load_lds(
                (const __attribute__((address_space(1))) void*)ga,
                (__attribute__((address_space(3))) void*)((char*)&As[0][0] + off),
                16, 0, 0);
        }
        // W: 64x32 el = 4096B = 256 x 16B loads (one per thread)
        {
            int r = tid >> 2, c4 = (tid & 3) * 8;
            const u16* gw = &Wp[(size_t)(n0 + r) * lda + k0 + c4];
            unsigned off = (unsigned)(wave * 64 * 16);
            __builtin_amdgcn_global_load_lds(
                (const __attribute__((address_space(1))) void*)gw,
                (__attribute__((address_space(3))) void*)((char*)&Ws[0][0] + off),
                16, 0, 0);
        }
        __syncthreads();
        bf16x8 af[2], bfr[2];
        #pragma unroll
        for (int mi = 0; mi < 2; ++mi)
            af[mi] = __builtin_bit_cast(bf16x8, *(const uint4*)&As[wm + mi * 16 + col][quad * 8]);
        #pragma unroll
        for (int ni = 0; ni < 2; ++ni)
            bfr[ni] = __builtin_bit_cast(bf16x8, *(const uint4*)&Ws[wn + ni * 16 + col][quad * 8]);
        #pragma unroll
        for (int mi = 0; mi < 2; ++mi)
            #pragma unroll
            for (int ni = 0; ni < 2; ++ni)
                acc[mi][ni] = __builtin_amdgcn_mfma_f32_16x16x32_bf16(
                    af[mi], bfr[ni], acc[mi][ni], 0, 0, 0);
        __syncthreads();
    }
    #pragma unroll
    for (int mi = 0; mi < 2; ++mi)
        #pragma unroll
        for (int ni = 0; ni < 2; ++ni)
            #pragma unroll
            for (int reg = 0; reg < 4; ++reg) {
                int rr = m0 + wm + mi * 16 + quad * 4 + reg;
                int cc = n0 + wn + ni * 16 + col;
                float v = acc[mi][ni][reg];
                if (MODE == 0) {
                    v += biasf[cc];
                    int i = rr >> 2, n = rr & 3;     // A rows are i*NB+n
                    if (cc < EMB) {
                        // q head-major: [n][h][i][d]
                        int h = cc >> 6, d = cc & 63;
                        outB0[(((size_t)(n * NH + h)) * L_SEQ + i) * HD + d] = f2b(v * 0.125f);
                    } else if (cc < 2 * EMB) {
                        int c2 = cc - EMB;
                        int h = c2 >> 6, d = c2 & 63;
                        outB1[(((size_t)(n * NH + h)) * L_SEQ + i) * HD + d] = f2b(v);
                    } else {
                        // vt[(n*EMB + e)*L + i]
                        outB2[((size_t)n * EMB + (cc - 2 * EMB)) * L_SEQ + i] = f2b(v);
                    }
                } else if (MODE == 2) {
                    v += biasf[cc];
                    v = 0.5f * v * (1.0f + erff(v * 0.70710678118654752f));
                    outB0[(size_t)rr * DFF + cc] = f2b(v);
                } else if (MODE == 4) {
                    float* o = z ? outF2 : outF;
                    o[(size_t)rr * EMB + cc] = v;
                } else {
                    atomicAdd(&outF[(size_t)rr * EMB + cc], v);
                }
            }
}

// qp_b[n,i,h,c] (bf16, h padded to 16) = sum_d q[n,h,i,d] p_w[h*64+d, c]
// qpb[n,h,i] = q . p_b   (q pre-scaled by 0.125 in QKV epilogue)
__global__ __launch_bounds__(256) void qp_kernel(
        const u16* __restrict__ qb, const void* __restrict__ p_w,
        const void* __restrict__ p_b, u16* __restrict__ qp_b,
        float* __restrict__ qpb, const int* __restrict__ flagp) {
    const int f32 = *flagp;
    int w = threadIdx.x >> 6, t = threadIdx.x & 63;
    int blk = blockIdx.x * 4 + w;        // (n*NH+h)*L + i
    int i = blk & 255;
    int h = (blk >> 8) % NH;
    int n = blk / (256 * NH);
    __shared__ float qs[4][64];
    // q head-major: contiguous 128B row per (n,h,i) -> coalesced
    qs[w][t] = b2f(qb[(((size_t)(n * NH + h)) * L_SEQ + i) * HD + t]);
    __syncthreads();
    float acc = 0.f;
    #pragma unroll 16
    for (int d = 0; d < 64; ++d)
        acc += qs[w][d] * ldE(p_w, (size_t)(h * HD + d) * HD + t, f32);
    qp_b[(((size_t)(n * L_SEQ + i)) * 16 + h) * 64 + t] = f2b(acc);
    float v = qs[w][t] * ldE(p_b, h * HD + t, f32);
    #pragma unroll
    for (int off = 32; off; off >>= 1) v += __shfl_down(v, off);
    if (t == 0) qpb[blk] = v;
}

// S[n,h,i,j] = sum_c qp_b[n,i,h,c] * pos[n,i,j,c] + qpb[n,h,i]
// One wave / block, j-dim split in 4 (blockIdx.y): 4096 blocks.
__global__ __launch_bounds__(64) void s2_mfma(
        const u16* __restrict__ qp_b, const float* __restrict__ qpb,
        const void* __restrict__ pos, float* __restrict__ S,
        const int* __restrict__ flagp) {
    const int f32 = *flagp;
    int wid = blockIdx.x;                // n*L + i
    int jh = blockIdx.y;                 // 0..3  (j-quarters)
    int i = wid & 255, n = wid >> 8;
    int lane = threadIdx.x;
    int quad = lane >> 4, col = lane & 15;
    const u16* qprow = qp_b + (((size_t)wid) * 16 + col) * 64;
    bf16x8 a0 = __builtin_bit_cast(bf16x8, *(const uint4*)(qprow + quad * 8));
    bf16x8 a1 = __builtin_bit_cast(bf16x8, *(const uint4*)(qprow + 32 + quad * 8));
    float qpb_r[4];
    #pragma unroll
    for (int reg = 0; reg < 4; ++reg) {
        int h = quad * 4 + reg;
        qpb_r[reg] = (h < NH) ? qpb[((size_t)n * NH + h) * L_SEQ + i] : 0.f;
    }
    #pragma unroll
    for (int tt = 0; tt < 4; ++tt) {
        int t = jh * 4 + tt;
        int j = t * 16 + col;
        size_t pbase = ((size_t)(n * L_SEQ + i) * L_SEQ + j) * HD;
        bf16x8 b0, b1;
        if (f32) {
            const float* pf = (const float*)pos + pbase;
            u16 tmp[16];
            #pragma unroll
            for (int c = 0; c < 8; ++c) tmp[c] = f2b(pf[quad * 8 + c]);
            #pragma unroll
            for (int c = 0; c < 8; ++c) tmp[8 + c] = f2b(pf[32 + quad * 8 + c]);
            b0 = *(bf16x8*)tmp;
            b1 = *(bf16x8*)(tmp + 8);
        } else {
            const u16* pb = (const u16*)pos + pbase;
            b0 = __builtin_bit_cast(bf16x8, *(const uint4*)(pb + quad * 8));
            b1 = __builtin_bit_cast(bf16x8, *(const uint4*)(pb + 32 + quad * 8));
        }
        f32x4 acc = (f32x4){0.f, 0.f, 0.f, 0.f};
        acc = __builtin_amdgcn_mfma_f32_16x16x32_bf16(a0, b0, acc, 0, 0, 0);
        acc = __builtin_amdgcn_mfma_f32_16x16x32_bf16(a1, b1, acc, 0, 0, 0);
        if (quad < 3) {
            #pragma unroll
            for (int reg = 0; reg < 4; ++reg) {
                int h = quad * 4 + reg;
                S[(((size_t)n * NH + h) * L_SEQ + i) * L_SEQ + j] = acc[reg] + qpb_r[reg];
            }
        }
    }
}

// MFMA attention, 4 waves per block cooperating on ONE 16-row i-tile:
// wave w owns j-quarter [w*64,(w+1)*64) for QK^T+partial softmax, and
// output-column group nt=w for PV. Partial max/sum combined via LDS
// (exact: global max = max of partials; sums taken against global max).
// 768 blocks x 4 waves = 12 waves/CU.
__global__ __launch_bounds__(256) void attn3_kernel(
        const u16* __restrict__ qb, const u16* __restrict__ kb,
        const u16* __restrict__ vt, const float* __restrict__ S,
        u16* __restrict__ ctxb) {
    __shared__ u16 p_lds[16][268];
    __shared__ float lds_m[4][16];
    __shared__ float lds_s[4][16];
    int b = blockIdx.x;
    int n = b / (NH * 16), rem = b % (NH * 16), h = rem >> 4, it = rem & 15;
    int wave = threadIdx.x >> 6, lane = threadIdx.x & 63;
    int quad = lane >> 4, col = lane & 15;
    int i0 = it * 16;

    const u16* qh = qb + ((size_t)(n * NH + h)) * L_SEQ * HD;
    const u16* kh = kb + ((size_t)(n * NH + h)) * L_SEQ * HD;

    const u16* qrow = qh + (size_t)(i0 + col) * HD;
    bf16x8 a0 = __builtin_bit_cast(bf16x8, *(const uint4*)(qrow + quad * 8));
    bf16x8 a1 = __builtin_bit_cast(bf16x8, *(const uint4*)(qrow + 32 + quad * 8));

    // QK^T for this wave's 4 j-tiles
    f32x4 sc[4];
    #pragma unroll
    for (int tt = 0; tt < 4; ++tt) {
        int t = wave * 4 + tt;
        const u16* krow = kh + (size_t)(t * 16 + col) * HD;
        bf16x8 b0 = __builtin_bit_cast(bf16x8, *(const uint4*)(krow + quad * 8));
        bf16x8 b1 = __builtin_bit_cast(bf16x8, *(const uint4*)(krow + 32 + quad * 8));
        f32x4 acc = (f32x4){0.f, 0.f, 0.f, 0.f};
        acc = __builtin_amdgcn_mfma_f32_16x16x32_bf16(a0, b0, acc, 0, 0, 0);
        acc = __builtin_amdgcn_mfma_f32_16x16x32_bf16(a1, b1, acc, 0, 0, 0);
        sc[tt] = acc;
    }

    // phase A: add S, per-wave partial row max
    #pragma unroll
    for (int reg = 0; reg < 4; ++reg) {
        const float* Srow = S + (((size_t)n * NH + h) * L_SEQ + i0 + quad * 4 + reg) * L_SEQ + col;
        float m = -1e30f;
        #pragma unroll
        for (int tt = 0; tt < 4; ++tt) {
            float v = sc[tt][reg] + Srow[(wave * 4 + tt) * 16];
            sc[tt][reg] = v;
            m = fmaxf(m, v);
        }
        #pragma unroll
        for (int off = 1; off < 16; off <<= 1) m = fmaxf(m, __shfl_xor(m, off));
        if (col == 0) lds_m[wave][quad * 4 + reg] = m;
    }
    __syncthreads();
    // global max per row
    float gm[4];
    #pragma unroll
    for (int reg = 0; reg < 4; ++reg) {
        int row = quad * 4 + reg;
        gm[reg] = fmaxf(fmaxf(lds_m[0][row], lds_m[1][row]),
                        fmaxf(lds_m[2][row], lds_m[3][row]));
    }
    // phase B: exp against global max, per-wave partial sums
    #pragma unroll
    for (int reg = 0; reg < 4; ++reg) {
        float sum = 0.f;
        #pragma unroll
        for (int tt = 0; tt < 4; ++tt) {
            float e = __expf(sc[tt][reg] - gm[reg]);
            sc[tt][reg] = e;
            sum += e;
        }
        #pragma unroll
        for (int off = 1; off < 16; off <<= 1) sum += __shfl_xor(sum, off);
        if (col == 0) lds_s[wave][quad * 4 + reg] = sum;
    }
    __syncthreads();
    // phase C: normalize, write P (this wave's j-quarter)
    #pragma unroll
    for (int reg = 0; reg < 4; ++reg) {
        int row = quad * 4 + reg;
        float gs = lds_s[0][row] + lds_s[1][row] + lds_s[2][row] + lds_s[3][row];
        float inv = 1.0f / gs;
        #pragma unroll
        for (int tt = 0; tt < 4; ++tt)
            p_lds[row][(wave * 4 + tt) * 16 + col] = f2b(sc[tt][reg] * inv);
    }
    __syncthreads();

    // PV: wave w computes output columns h*64 + w*16 + col
    bf16x8 ap[8];
    #pragma unroll
    for (int kt = 0; kt < 8; ++kt)
        ap[kt] = __builtin_bit_cast(bf16x8, *(const uint4*)&p_lds[col][kt * 32 + quad * 8]);
    {
        const u16* vrow = vt + ((size_t)n * EMB + h * HD + wave * 16 + col) * L_SEQ;
        f32x4 acc = (f32x4){0.f, 0.f, 0.f, 0.f};
        #pragma unroll
        for (int kt = 0; kt < 8; ++kt) {
            bf16x8 bp = __builtin_bit_cast(bf16x8, *(const uint4*)(vrow + kt * 32 + quad * 8));
            acc = __builtin_amdgcn_mfma_f32_16x16x32_bf16(ap[kt], bp, acc, 0, 0, 0);
        }
        #pragma unroll
        for (int reg = 0; reg < 4; ++reg) {
            int ii = i0 + quad * 4 + reg;
            ctxb[((size_t)ii * NB + n) * EMB + h * HD + wave * 16 + col] = f2b(acc[reg]);
        }
    }
}

// Block-wide sum over 256 threads via wave shuffle + 4-word LDS.
__device__ __forceinline__ float blk_sum(float v, volatile float* ws, int wave, int lane) {
    #pragma unroll
    for (int off = 32; off; off >>= 1) v += __shfl_xor(v, off);
    if (lane == 0) ws[wave] = v;
    __syncthreads();
    float s = ws[0] + ws[1] + ws[2] + ws[3];
    __syncthreads();
    return s;
}

// ln1: y = p0 + p1 + src + out_bias; LN -> x1b (bf16); y2 = LN_out + lin2_bias.
__global__ void ln1_kernel(const float* __restrict__ p0, const float* __restrict__ p1,
                           const void* __restrict__ src, const float* __restrict__ biasf,
                           const void* __restrict__ g, const void* __restrict__ b,
                           u16* __restrict__ x1b, float* __restrict__ y2,
                           const int* __restrict__ flagp) {
    const int f32 = *flagp;
    int r = blockIdx.x;
    int t = threadIdx.x;
    int wave = t >> 6, lane = t & 63;
    __shared__ float ws[4];
    float x[3];
    #pragma unroll
    for (int p = 0; p < 3; ++p) {
        int e = t + p * 256;
        size_t oi = (size_t)r * EMB + e;
        x[p] = p0[oi] + p1[oi] + ldE(src, oi, f32) + biasf[2304 + e];
    }
    float mean = blk_sum(x[0] + x[1] + x[2], ws, wave, lane) * (1.0f / EMB);
    float d0 = x[0] - mean, d1 = x[1] - mean, d2 = x[2] - mean;
    float var = blk_sum(d0 * d0 + d1 * d1 + d2 * d2, ws, wave, lane) * (1.0f / EMB);
    float rstd = rsqrtf(var + 1e-5f);
    float vs[3] = {d0, d1, d2};
    #pragma unroll
    for (int p = 0; p < 3; ++p) {
        int e = t + p * 256;
        float v = vs[p] * rstd * ldE(g, e, f32) + ldE(b, e, f32);
        size_t oi = (size_t)r * EMB + e;
        x1b[oi] = f2b(v);
        y2[oi] = v + biasf[6144 + e];
    }
}

// ln2 (final): LN(y2) -> d_out runtime dtype.
__global__ void ln2_kernel(const float* __restrict__ X, const void* __restrict__ g,
                           const void* __restrict__ b, void* __restrict__ outAny,
                           const int* __restrict__ flagp) {
    const int f32 = *flagp;
    int r = blockIdx.x;
    int t = threadIdx.x;
    int wave = t >> 6, lane = t & 63;
    __shared__ float ws[4];
    float x0 = X[(size_t)r * EMB + t];
    float x1 = X[(size_t)r * EMB + t + 256];
    float x2 = X[(size_t)r * EMB + t + 512];
    float mean = blk_sum(x0 + x1 + x2, ws, wave, lane) * (1.0f / EMB);
    float d0 = x0 - mean, d1 = x1 - mean, d2 = x2 - mean;
    float var = blk_sum(d0 * d0 + d1 * d1 + d2 * d2, ws, wave, lane) * (1.0f / EMB);
    float rstd = rsqrtf(var + 1e-5f);
    float vs[3] = {d0, d1, d2};
    #pragma unroll
    for (int p = 0; p < 3; ++p) {
        int e = t + p * 256;
        float v = vs[p] * rstd * ldE(g, e, f32) + ldE(b, e, f32);
        size_t oi = (size_t)r * EMB + e;
        if (f32) ((float*)outAny)[oi] = v;
        else     ((bf16*)outAny)[oi] = __float2bfloat16(v);
    }
}

extern "C" void kernel_launch(void* const* d_in, const int* in_sizes, int n_in,
                              void* d_out, int out_size, void* d_ws, size_t ws_size,
                              hipStream_t stream) {
    const void* src    = d_in[0];
    const void* pos    = d_in[1];
    const void* q_w    = d_in[2];
    const void* q_b    = d_in[3];
    const void* k_w    = d_in[4];
    const void* k_b    = d_in[5];
    const void* v_w    = d_in[6];
    const void* v_b    = d_in[7];
    const void* p_w    = d_in[8];
    const void* p_b    = d_in[9];
    const void* out_w  = d_in[10];
    const void* out_b  = d_in[11];
    const void* lin1_w = d_in[12];
    const void* lin1_b = d_in[13];
    const void* lin2_w = d_in[14];
    const void* lin2_b = d_in[15];
    const void* n1_g   = d_in[16];
    const void* n1_b   = d_in[17];
    const void* n2_g   = d_in[18];
    const void* n2_b   = d_in[19];

    float* f = (float*)d_ws;
    int*   flagp = (int*)f;                              // 16
    float* biasf = f + 16;                               // 6912
    u16*   xb    = (u16*)(f + 6928);                     // 393216 f
    u16*   wqkv  = (u16*)(f + 400144);                   // 884736 f (dead after QKV gemm)
    u16*   owb   = (u16*)(f + 1284880);                  // 294912 f
    u16*   l1b   = (u16*)(f + 1579792);                  // 1179648 f
    u16*   l2b   = (u16*)(f + 2759440);                  // 1179648 f
    u16*   qbp   = (u16*)(f + 3939088);                  // 393216 f  [n][h][i][d]
    u16*   kbp   = (u16*)(f + 4332304);                  // 393216 f  [n][h][i][d]
    u16*   vtb   = (u16*)(f + 4725520);                  // 393216 f  vt[n][e][i]
    u16*   qp_b  = (u16*)(f + 5118736);                  // 524288 f
    float* qpb   = f + 5643024;                          // 12288
    float* S     = f + 5655312;                          // 3145728 (ends 8801040)
    u16*   ctxb  = (u16*)(f + 8801040);                  // 393216 f (ends 9194256)
    // overlays (regions dead at time of use):
    u16*   ffb   = (u16*)S;                              // S[0 : 1572864]
    float* y2    = S + 1572864;                          // S[1572864 : 2359296]
    float* pOut1 = S + 2359296;                          // S[2359296 : 3145728]
    float* pOut0 = f + 400144;                           // wqkv region (dead)
    u16*   x1b   = vtb;                                  // vt dead after attn3

    pack_all<<<3867, 256, 0, stream>>>(xb, wqkv, owb, l1b, l2b, biasf,
                                       src, q_w, k_w, v_w, out_w, lin1_w, lin2_w,
                                       q_b, k_b, v_b, out_b, lin1_b, lin2_b, flagp);

    // QKV fused GEMM (N=2304); q,k head-major; V transposed. 576 blocks.
    mfma_gemm<0><<<dim3(36, 16), 256, 0, stream>>>(
        xb, wqkv, biasf, qbp, kbp, vtb, nullptr, nullptr, EMB, EMB, 0);

    // position scores
    qp_kernel<<<NB * NH * L_SEQ / 4, 256, 0, stream>>>(qbp, p_w, p_b, qp_b, qpb, flagp);
    s2_mfma<<<dim3(NB * L_SEQ, 4), 64, 0, stream>>>(qp_b, qpb, pos, S, flagp);

    // MFMA attention (4 coop waves / block, 768 blocks = 12 waves/CU)
    attn3_kernel<<<NB * NH * 16, 256, 0, stream>>>(qbp, kbp, vtb, S, ctxb);

    // out projection, split-K=2 -> partials pOut0/pOut1 (bias+residual in ln1). 384 blocks.
    mfma_gemm<4><<<dim3(12, 16, 2), 256, 0, stream>>>(
        ctxb, owb, nullptr, nullptr, nullptr, nullptr, pOut0, pOut1, 384, EMB, 384);

    // ln1: reduce partials + src + out_bias, LN -> x1b; y2 = LN + lin2_bias
    ln1_kernel<<<1024, 256, 0, stream>>>(pOut0, pOut1, src, biasf, n1_g, n1_b,
                                         x1b, y2, flagp);

    // lin1 + GELU -> ffb. 768 blocks.
    mfma_gemm<2><<<dim3(48, 16), 256, 0, stream>>>(
        x1b, l1b, biasf + 3072, ffb, nullptr, nullptr, nullptr, nullptr, EMB, EMB, 0);

    // lin2, split-K=4, atomic accumulate into y2 (pre-initialized by ln1). 768 blocks.
    mfma_gemm<5><<<dim3(12, 16, 4), 256, 0, stream>>>(
        ffb, l2b, nullptr, nullptr, nullptr, nullptr, y2, nullptr, 768, DFF, 768);

    ln2_kernel<<<1024, 256, 0, stream>>>(y2, n2_g, n2_b, d_out, flagp);
}